// Round 5
// baseline (273.236 us; speedup 1.0000x reference)
//
#include <hip/hip_runtime.h>

// ---------------------------------------------------------------------------
// Bidirectional Mamba block, MI355X. Round 25:
//  - kconv3 re-partitioned for TLP: was 256 blocks = 1 block/CU = 1 wave/SIMD,
//    95% latency-stalled (VALUBusy 4.3%, measured == per-thread inst count /
//    duration). Now grid t16 x hq8 (32-l tiles, 512 blocks = 2/CU) x 512 thr
//    (8 waves) = 16 waves/CU = 4/SIMD. Wave = 16co x 16l, 54 K-steps.
//    LDS 46.6 -> 31.1 KB. Same math, same layouts (ds_read bank distribution
//    verified uniform; no swizzle needed).
//  - knorm fused in kconv3 (R24); koutg/x_dbl/conv on MFMA (R21-24).
// Shapes: B=4, C=64, D=128, L=4096 (l = h*256 + w*16 + t), N=16, R=8.
// ---------------------------------------------------------------------------

#define NL 4096

typedef unsigned short u16;
typedef unsigned int u32;
typedef __attribute__((ext_vector_type(8))) short bf16x8;
typedef __attribute__((ext_vector_type(4))) float f32x4;

__device__ __forceinline__ float siluf_(float x) {
  return x * __builtin_amdgcn_rcpf(1.f + __expf(-x));
}
__device__ __forceinline__ float softplusf_(float x) {
  return (x > 20.f) ? x : __logf(1.f + __expf(x));
}
__device__ __forceinline__ u16 f2bf(float f) {
  u32 u = __float_as_uint(f);
  u += 0x7fffu + ((u >> 16) & 1u);
  return (u16)(u >> 16);
}
__device__ __forceinline__ float bflo(u32 v) { return __uint_as_float(v << 16); }
__device__ __forceinline__ float bfhi(u32 v) { return __uint_as_float(v & 0xFFFF0000u); }

// Sum over the 16-lane DPP row via rotations 1,2,4,8 (VALU pipe, no DS).
__device__ __forceinline__ float rowsum16_(float p) {
  int q;
  q = __builtin_amdgcn_mov_dpp(__float_as_int(p), 0x121, 0xf, 0xf, false);
  p += __int_as_float(q);
  q = __builtin_amdgcn_mov_dpp(__float_as_int(p), 0x122, 0xf, 0xf, false);
  p += __int_as_float(q);
  q = __builtin_amdgcn_mov_dpp(__float_as_int(p), 0x124, 0xf, 0xf, false);
  p += __int_as_float(q);
  q = __builtin_amdgcn_mov_dpp(__float_as_int(p), 0x128, 0xf, 0xf, false);
  p += __int_as_float(q);
  return p;
}

// Per-b slab offsets (fp32 elements; bf16 regions use u16 views at same base)
#define OXZ  0u          // xz [256][4096] fp32
#define OUCF 1048576u    // ucf [128][4096] bf16 (u16 view)
#define OUCB 1572864u    // ucb [128][4096] bf16 (flipped coords)
#define ODLF 2424832u    // dlf [128][4096] bf16
#define ODLB 2949120u    // dlb [128][4096] bf16 (flipped coords)
#define OYF  3473408u    // yf [128][4096] fp32
#define OYB  3997696u    // yb [128][4096] fp32 (flipped coords)
#define OO   4521984u    // scan scratch: P [262144] S [262144] fp32
#define OO2  5046272u    // bct bf16 until kscanC; then o2 [4096][64] fp32
#define PER_B 5570560u
// Wbf [27][64][64] bf16 lives at ws + bcnt*PER_B (55296 floats)

#define NCH 64   // scan chunks
#define CL  64   // chunk length

// 1. xz[e,l] = sum_c in_proj_w[e,c] * seq[c,l].
__global__ __launch_bounds__(256) void kxz(
    const float* __restrict__ x, const float* __restrict__ wip,
    float* __restrict__ ws, int b0) {
  int bi = blockIdx.y, gb = b0 + bi;
  float* s = ws + (size_t)bi * PER_B;
  int bid = blockIdx.x;
  int h = bid >> 4, w = bid & 15;
  int tid = threadIdx.x;
  __shared__ float xs[64][16];
  for (int i = tid; i < 1024; i += 256) {
    int c = i >> 4, t = i & 15;
    xs[c][t] = x[(size_t)(gb * 64 + c) * NL + t * 256 + h * 16 + w];
  }
  __syncthreads();
  int e = tid;
  float acc[16];
#pragma unroll
  for (int t = 0; t < 16; ++t) acc[t] = 0.f;
  for (int c = 0; c < 64; ++c) {
    float wv = wip[e * 64 + c];
#pragma unroll
    for (int t = 0; t < 16; ++t) acc[t] = fmaf(wv, xs[c][t], acc[t]);
  }
  float4* dst = (float4*)(s + OXZ + (size_t)e * NL + h * 256 + w * 16);
#pragma unroll
  for (int q = 0; q < 4; ++q)
    dst[q] = make_float4(acc[q * 4], acc[q * 4 + 1], acc[q * 4 + 2], acc[q * 4 + 3]);
}

// 2. Fused prep per (bi, dir, 32-l tile): dwconv+silu, x_dbl via MFMA, delta,
// bct. Grid x = 256 (lt 128 x dir 2).
__global__ __launch_bounds__(256) void k2prep(
    const float* __restrict__ cwf, const float* __restrict__ cbf,
    const float* __restrict__ xpf, const float* __restrict__ dtwf,
    const float* __restrict__ dtbf,
    const float* __restrict__ cwb, const float* __restrict__ cbb,
    const float* __restrict__ xpb, const float* __restrict__ dtwb,
    const float* __restrict__ dtbb,
    float* __restrict__ ws) {
  int bi = blockIdx.y;
  float* s = ws + (size_t)bi * PER_B;
  int bx = blockIdx.x;
  int lt = bx >> 1, dir = bx & 1;
  int l0 = lt * 32;
  int lout0 = dir ? (127 - lt) * 32 : l0;   // output base (flipped for bwd)
  int tid = threadIdx.x;

  __shared__ float pool[128 * 40];   // X[128][40] during dwconv; xds after
  __shared__ u16 uct[32][136];       // uc transposed bf16 (d-contig, 16B rows)
  float (*X)[40] = (float(*)[40])pool;

  for (int i = tid; i < 128 * 38; i += 256) {
    int d = i / 38, j = i - d * 38;
    int l = l0 - 3 + j;
    X[d][j] = (l >= 0 && l < NL) ? s[OXZ + (size_t)d * NL + l] : 0.f;
  }
  __syncthreads();

  const float* cw = dir ? cwb : cwf;
  const float* cb = dir ? cbb : cbf;
  u16* ucg = (u16*)(s + (dir ? OUCB : OUCF));
  for (int i = tid; i < 128 * 32; i += 256) {
    int d = i >> 5, li = i & 31;
    float a = cb[d];
    if (dir == 0) {
#pragma unroll
      for (int k = 0; k < 4; ++k) a = fmaf(cw[d * 4 + k], X[d][li + k], a);
    } else {
#pragma unroll
      for (int k = 0; k < 4; ++k) a = fmaf(cw[d * 4 + k], X[d][37 - li - k], a);
    }
    a = siluf_(a);
    u16 ab = f2bf(a);
    uct[li][d] = ab;
    ucg[(size_t)d * NL + lout0 + li] = ab;
  }
  __syncthreads();  // X dead; pool becomes xds [40][33]

  // x_dbl via MFMA 16x16x32: D[e 48][l 32], K=128. Units (et,lt2) = 6 over
  // 4 waves (waves 0,1 take two units).
  float* xds = pool;
  {
    int wid = tid >> 6, lane = tid & 63;
    int n16 = lane & 15, kg = lane >> 4;
    const float* xp = dir ? xpb : xpf;
#pragma unroll
    for (int rep = 0; rep < 2; ++rep) {
      int id = wid + rep * 4;
      if (id < 6) {
        int et = id >> 1, lt2 = id & 1;
        f32x4 acc = {};
#pragma unroll
        for (int ks = 0; ks < 4; ++ks) {
          bf16x8 bfrag = *(const bf16x8*)&uct[lt2 * 16 + n16][ks * 32 + kg * 8];
          int e = et * 16 + n16;
          int ec = (e < 40) ? e : 39;        // clamp addr; rows >=40 discarded
          const float* pa = xp + ec * 128 + ks * 32 + kg * 8;
          float4 a0 = *(const float4*)pa;
          float4 a1 = *(const float4*)(pa + 4);
          bf16x8 af;
          af[0] = (short)f2bf(a0.x); af[1] = (short)f2bf(a0.y);
          af[2] = (short)f2bf(a0.z); af[3] = (short)f2bf(a0.w);
          af[4] = (short)f2bf(a1.x); af[5] = (short)f2bf(a1.y);
          af[6] = (short)f2bf(a1.z); af[7] = (short)f2bf(a1.w);
          acc = __builtin_amdgcn_mfma_f32_16x16x32_bf16(af, bfrag, acc, 0, 0, 0);
        }
        // D layout: col = lane&15 (l), row = kg*4 + rg (e within 16-tile)
#pragma unroll
        for (int rg = 0; rg < 4; ++rg) {
          int e = et * 16 + kg * 4 + rg;
          if (e < 40) xds[e * 33 + lt2 * 16 + n16] = acc[rg];
        }
      }
    }
  }
  __syncthreads();

  const float* dtw = dir ? dtwb : dtwf;
  const float* dtb = dir ? dtbb : dtbf;
  u16* dlg = (u16*)(s + (dir ? ODLB : ODLF));
  for (int i = tid; i < 128 * 32; i += 256) {
    int d = i >> 5, li = i & 31;
    float pre = dtb[d];
#pragma unroll
    for (int r = 0; r < 8; ++r)
      pre = fmaf(dtw[d * 8 + r], xds[r * 33 + li], pre);
    dlg[(size_t)d * NL + lout0 + li] = f2bf(softplusf_(pre));
  }
  u16* bctp = (u16*)(s + OO2);
  for (int i = tid; i < 32 * 32; i += 256) {
    int li = i >> 5, k = i & 31;
    bctp[((size_t)dir * 4096 + lout0 + li) * 32 + k] = f2bf(xds[(8 + k) * 33 + li]);
  }
}

// 5a. Phase A: 16 d-rows/block; chunk bct (bf16) staged to fp32 LDS;
// ushort8 dl/uc loads = 8 steps per load pair.
__global__ __launch_bounds__(256) void kscanA(
    const float* __restrict__ Alf, const float* __restrict__ Alb,
    float* __restrict__ ws) {
  int bi = blockIdx.y;
  float* s = ws + (size_t)bi * PER_B;
  int xid = blockIdx.x;
  int chunk = xid >> 4, dir = (xid >> 3) & 1, d8 = xid & 7;
  int tid = threadIdx.x;
  int wv = tid >> 6, lane = tid & 63;
  int n = lane & 15, g = lane >> 4;
  int d = d8 * 16 + wv * 4 + g;
  int l0 = chunk * CL;
  __shared__ float bl[CL * 32];
  {
    const u16* bctp = (const u16*)(s + OO2) + ((size_t)dir * 4096 + l0) * 32;
    for (int i = tid; i < CL * 32; i += 256)
      bl[i] = __uint_as_float(((u32)bctp[i]) << 16);
  }
  __syncthreads();
  const u16* ucp = (const u16*)(s + (dir ? OUCB : OUCF)) + (size_t)d * NL + l0;
  const u16* dlp = (const u16*)(s + (dir ? ODLB : ODLF)) + (size_t)d * NL + l0;
  float A = -__expf((dir ? Alb : Alf)[d * 16 + n]);
  float P = 1.f, S = 0.f;
  for (int i0 = 0; i0 < CL; i0 += 8) {
    uint4 dq = *(const uint4*)(dlp + i0);
    uint4 uq = *(const uint4*)(ucp + i0);
    float dv[8] = {bflo(dq.x), bfhi(dq.x), bflo(dq.y), bfhi(dq.y),
                   bflo(dq.z), bfhi(dq.z), bflo(dq.w), bfhi(dq.w)};
    float uv[8] = {bflo(uq.x), bfhi(uq.x), bflo(uq.y), bfhi(uq.y),
                   bflo(uq.z), bfhi(uq.z), bflo(uq.w), bfhi(uq.w)};
#pragma unroll
    for (int j = 0; j < 8; ++j) {
      float dA = __expf(dv[j] * A);
      S = fmaf(dA, S, dv[j] * bl[(i0 + j) * 32 + n] * uv[j]);
      P *= dA;
    }
  }
  size_t cidx = ((size_t)(chunk * 2 + dir) * 128 + d) * 16 + n;
  s[OO + cidx] = P;
  s[OO + 262144u + cidx] = S;
}

// 5b. Phase B: carry combine.
__global__ __launch_bounds__(64) void kscanB(float* __restrict__ ws) {
  int bi = blockIdx.y;
  float* s = ws + (size_t)bi * PER_B;
  int dir = blockIdx.x >> 5, dblk = blockIdx.x & 31;
  int tid = threadIdx.x;
  size_t base = (size_t)dir * 2048 + dblk * 64 + tid;
  float carry = 0.f;
#pragma unroll 4
  for (int c = 0; c < NCH; ++c) {
    size_t idx = (size_t)c * 4096 + base;
    float pv = s[OO + idx], sv = s[OO + 262144u + idx];
    s[OO + 262144u + idx] = carry;
    carry = fmaf(pv, carry, sv);
  }
}

// 5c. Phase C: seeded re-scan; bf16 inputs; DPP row-sum; ps[16][65] staging.
__global__ __launch_bounds__(256) void kscanC(
    const float* __restrict__ Alf, const float* __restrict__ Df,
    const float* __restrict__ Alb, const float* __restrict__ Db,
    float* __restrict__ ws) {
  int bi = blockIdx.y;
  float* s = ws + (size_t)bi * PER_B;
  int xid = blockIdx.x;
  int chunk = xid >> 4, dir = (xid >> 3) & 1, d8 = xid & 7;
  int tid = threadIdx.x;
  int wv = tid >> 6, lane = tid & 63;
  int n = lane & 15, g = lane >> 4;
  int d = d8 * 16 + wv * 4 + g;
  int l0 = chunk * CL;
  __shared__ float bl[CL * 32];
  __shared__ float ps[16][65];
  {
    const u16* bctp = (const u16*)(s + OO2) + ((size_t)dir * 4096 + l0) * 32;
    for (int i = tid; i < CL * 32; i += 256)
      bl[i] = __uint_as_float(((u32)bctp[i]) << 16);
  }
  __syncthreads();
  const u16* ucp = (const u16*)(s + (dir ? OUCB : OUCF)) + (size_t)d * NL + l0;
  const u16* dlp = (const u16*)(s + (dir ? ODLB : ODLF)) + (size_t)d * NL + l0;
  float* ybase = s + (dir ? OYB : OYF);
  float A = -__expf((dir ? Alb : Alf)[d * 16 + n]);
  float Dv = (dir ? Db : Df)[d];
  size_t cidx = ((size_t)(chunk * 2 + dir) * 128 + d) * 16 + n;
  float h = s[OO + 262144u + cidx];
  int prow = wv * 4 + g;
  for (int i0 = 0; i0 < CL; i0 += 8) {
    uint4 dq = *(const uint4*)(dlp + i0);
    uint4 uq = *(const uint4*)(ucp + i0);
    float dv[8] = {bflo(dq.x), bfhi(dq.x), bflo(dq.y), bfhi(dq.y),
                   bflo(dq.z), bfhi(dq.z), bflo(dq.w), bfhi(dq.w)};
    float uv[8] = {bflo(uq.x), bfhi(uq.x), bflo(uq.y), bfhi(uq.y),
                   bflo(uq.z), bfhi(uq.z), bflo(uq.w), bfhi(uq.w)};
#pragma unroll
    for (int j = 0; j < 8; ++j) {
      int i = i0 + j;
      float dA = __expf(dv[j] * A);
      h = fmaf(dA, h, dv[j] * bl[i * 32 + n] * uv[j]);
      float p = rowsum16_(h * bl[i * 32 + 16 + n]);
      if (n == 0) ps[prow][i] = fmaf(uv[j], Dv, p);
    }
  }
  __syncthreads();
  for (int i = tid; i < 16 * CL; i += 256) {
    int row = i >> 6, col = i & 63;
    ybase[(size_t)(d8 * 16 + row) * NL + l0 + col] = ps[row][col];
  }
}

// 6. Fused gate + out-proj via MFMA. Block = 32-l tile.
// Gate: otb[l 32][d 128 pad 136] bf16 (transposed, 16B rows). Out-proj:
// D[c 64][l 32], K=128; wave ct handles both l2 tiles; float4 stores.
__global__ __launch_bounds__(256) void koutg(
    const float* __restrict__ wout, float* __restrict__ ws) {
  int bi = blockIdx.y;
  float* s = ws + (size_t)bi * PER_B;
  int lt = blockIdx.x;
  int l0 = lt * 32;
  int tid = threadIdx.x;
  __shared__ u16 otb[32][136];
  for (int i = tid; i < 128 * 32; i += 256) {
    int d = i >> 5, li = i & 31;
    int l = l0 + li;
    float z = s[OXZ + (size_t)(128 + d) * NL + l];
    float v = s[OYF + (size_t)d * NL + l] + s[OYB + (size_t)d * NL + (NL - 1 - l)];
    otb[li][d] = f2bf(v * siluf_(z));
  }
  __syncthreads();
  int wid = tid >> 6, lane = tid & 63;
  int n16 = lane & 15, kg = lane >> 4;
  f32x4 acc[2] = {};   // [l2 tile]
  const float* wr = wout + (size_t)(wid * 16 + n16) * 128 + kg * 8;
#pragma unroll
  for (int ks = 0; ks < 4; ++ks) {
    const float* pa = wr + ks * 32;
    float4 a0 = *(const float4*)pa;
    float4 a1 = *(const float4*)(pa + 4);
    bf16x8 af;
    af[0] = (short)f2bf(a0.x); af[1] = (short)f2bf(a0.y);
    af[2] = (short)f2bf(a0.z); af[3] = (short)f2bf(a0.w);
    af[4] = (short)f2bf(a1.x); af[5] = (short)f2bf(a1.y);
    af[6] = (short)f2bf(a1.z); af[7] = (short)f2bf(a1.w);
    bf16x8 b0 = *(const bf16x8*)&otb[n16][ks * 32 + kg * 8];
    bf16x8 b1 = *(const bf16x8*)&otb[16 + n16][ks * 32 + kg * 8];
    acc[0] = __builtin_amdgcn_mfma_f32_16x16x32_bf16(af, b0, acc[0], 0, 0, 0);
    acc[1] = __builtin_amdgcn_mfma_f32_16x16x32_bf16(af, b1, acc[1], 0, 0, 0);
  }
  // D: col = lane&15 (l), row = kg*4+rg (c in 16-tile); rg = consecutive c.
#pragma unroll
  for (int l2 = 0; l2 < 2; ++l2) {
    float4 st = make_float4(acc[l2][0], acc[l2][1], acc[l2][2], acc[l2][3]);
    *(float4*)&s[OO2 + (size_t)(l0 + l2 * 16 + n16) * 64 + wid * 16 + kg * 4] = st;
  }
}

// 6.5. Weight prep: Wbf[27][co 64][ci 64] bf16 at ws + bcnt*PER_B.
__global__ __launch_bounds__(256) void kprepw(
    const float* __restrict__ pw, float* __restrict__ wdst) {
  int off = blockIdx.x;
  u16* wb = (u16*)wdst;
  int tid = threadIdx.x;
  for (int i = tid; i < 4096; i += 256) {
    int co = i >> 6, ci = i & 63;
    wb[off * 4096 + i] = f2bf(pw[(size_t)(co * 64 + ci) * 27 + off]);
  }
}

// 7. conv3d (bf16 implicit GEMM on MFMA) + FUSED 1x1x1 norm mix.
// Block tile [64 co][32 l] = one t-plane x 2 h-rows; grid = t(16) x hq(8),
// 512 threads / 8 waves; wave (cq = wid>>1, oh = wid&1) = 16co x 16l.
// LDS: halo Xs[tt 3][hh 4][ww 18][ci 64 pad 72] bf16 (31.1 KB); after MFMA
// aliased as cx[ci 64][lp 32 pad 33] fp32 = conv+bias+residual, then
// out[co] = nb + sum_ci nw[co,ci]*cx[ci] -> global.
__global__ __launch_bounds__(512) void kconv3(
    const float* __restrict__ pb, const float* __restrict__ nw,
    const float* __restrict__ nb, const float* __restrict__ xin,
    float* __restrict__ out, const u16* __restrict__ wb,
    float* __restrict__ ws, int b0) {
  int bi = blockIdx.y, gb = b0 + bi;
  float* s = ws + (size_t)bi * PER_B;
  int t = blockIdx.x >> 3, hq = blockIdx.x & 7;
  int h0 = hq * 2;
  int tid = threadIdx.x;
  const float* xr = s + OO2;              // o2 in c-major reshape view

  __shared__ u16 Xs[3 * 4 * 18 * 72];     // 31104 B; later aliased as cx
  float* cx = (float*)Xs;                 // cx[64][33] = 8448 B
  // zero (covers t/h/w halo padding)
  {
    u32* xz32 = (u32*)Xs;
    for (int i = tid; i < 3 * 4 * 18 * 72 / 2; i += 512) xz32[i] = 0u;
  }
  __syncthreads();
  // stage valid rows, transposed to ci-contiguous bf16
  for (int i = tid; i < 12 * 64 * 4; i += 512) {
    int wq = i & 3, ci = (i >> 2) & 63, rowc = i >> 8;  // rowc 0..11
    int tt = rowc >> 2, hh = rowc & 3;
    int ts = t + tt - 1, hs = h0 + hh - 1;
    if (ts < 0 || ts > 15 || hs < 0 || hs > 15) continue;
    float4 v = *(const float4*)(xr + (size_t)ci * NL + ts * 256 + hs * 16 + wq * 4);
    int rb = (tt * 4 + hh) * 18 + 1 + wq * 4;
    Xs[(rb + 0) * 72 + ci] = f2bf(v.x);
    Xs[(rb + 1) * 72 + ci] = f2bf(v.y);
    Xs[(rb + 2) * 72 + ci] = f2bf(v.z);
    Xs[(rb + 3) * 72 + ci] = f2bf(v.w);
  }
  __syncthreads();

  int wid = tid >> 6, lane = tid & 63;
  int cq = wid >> 1, oh = wid & 1;
  int n16 = lane & 15, kg = lane >> 4;   // k-group 0..3 (8 ci each)
  f32x4 acc = {};

  // A: Wbf[off][co][ci]; lane row co = cq*16 + n16, k = kg*8 + st*32 + j
  const u16* wbA = wb + (size_t)(cq * 16 + n16) * 64 + kg * 8;
  for (int kt = 0; kt < 3; ++kt)
    for (int kh = 0; kh < 3; ++kh) {
      int rbase = (kt * 4 + oh + kh) * 18 + n16;
#pragma unroll
      for (int kw = 0; kw < 3; ++kw) {
        int off = (kt * 3 + kh) * 3 + kw;
        int r0 = rbase + kw;
        const u16* pa = wbA + off * 4096;
#pragma unroll
        for (int st = 0; st < 2; ++st) {
          int kb = st * 32;
          bf16x8 a0 = *(const bf16x8*)(pa + kb);
          bf16x8 b0 = *(const bf16x8*)(&Xs[r0 * 72 + kb + kg * 8]);
          acc = __builtin_amdgcn_mfma_f32_16x16x32_bf16(a0, b0, acc, 0, 0, 0);
        }
      }
    }
  __syncthreads();  // all Xs reads done; safe to overwrite with cx

  // cx[co][lp] = conv + bias + residual.
  // C/D layout: col = lane&15 (w), row = kg*4 + rg (co within 16-subtile)
  {
    int lp = oh * 16 + n16;
    int lg = t * 256 + h0 * 16 + lp;
#pragma unroll
    for (int rg = 0; rg < 4; ++rg) {
      int co = cq * 16 + kg * 4 + rg;
      cx[co * 33 + lp] = acc[rg] + pb[co] +
                         xin[(size_t)(gb * 64 + co) * NL + lg];
    }
  }
  __syncthreads();

  // 1x1x1 norm mix: out[co2][lp] = nb + sum_ci nw[co2,ci] * cx[ci][lp]
  {
    int co2 = tid >> 3, pq = tid & 7;   // 4 l each
    float mac[4] = {0.f, 0.f, 0.f, 0.f};
    for (int ci = 0; ci < 64; ci += 4) {
      float4 w4 = *(const float4*)&nw[co2 * 64 + ci];
      float wv[4] = {w4.x, w4.y, w4.z, w4.w};
#pragma unroll
      for (int cc = 0; cc < 4; ++cc) {
        float4 a = *(const float4*)&cx[(ci + cc) * 33 + pq * 4];
        mac[0] = fmaf(wv[cc], a.x, mac[0]);
        mac[1] = fmaf(wv[cc], a.y, mac[1]);
        mac[2] = fmaf(wv[cc], a.z, mac[2]);
        mac[3] = fmaf(wv[cc], a.w, mac[3]);
      }
    }
    float bias = nb[co2];
    *(float4*)(out + (size_t)(gb * 64 + co2) * NL + t * 256 + h0 * 16 + pq * 4) =
        make_float4(mac[0] + bias, mac[1] + bias, mac[2] + bias, mac[3] + bias);
  }
}

// ---------------------------------------------------------------------------
extern "C" void kernel_launch(void* const* d_in, const int* in_sizes, int n_in,
                              void* d_out, int out_size, void* d_ws, size_t ws_size,
                              hipStream_t stream) {
  const float* x    = (const float*)d_in[0];
  const float* wip  = (const float*)d_in[1];
  const float* cwf  = (const float*)d_in[2];
  const float* cbf  = (const float*)d_in[3];
  const float* xpf  = (const float*)d_in[4];
  const float* dtwf = (const float*)d_in[5];
  const float* dtbf = (const float*)d_in[6];
  const float* Alf  = (const float*)d_in[7];
  const float* Df   = (const float*)d_in[8];
  const float* cwb  = (const float*)d_in[9];
  const float* cbb  = (const float*)d_in[10];
  const float* xpb  = (const float*)d_in[11];
  const float* dtwb = (const float*)d_in[12];
  const float* dtbb = (const float*)d_in[13];
  const float* Alb  = (const float*)d_in[14];
  const float* Db   = (const float*)d_in[15];
  const float* wout = (const float*)d_in[16];
  const float* pw   = (const float*)d_in[17];
  const float* pb   = (const float*)d_in[18];
  const float* nw   = (const float*)d_in[19];
  const float* nb   = (const float*)d_in[20];

  const size_t PER_B_BYTES = (size_t)PER_B * 4;  // 22,282,240 per batch slab
  const size_t WB_BYTES = 27u * 64u * 64u * 2u;  // 221,184 (Wbf bf16)
  int bcnt;
  if (ws_size >= 4 * PER_B_BYTES + WB_BYTES) bcnt = 4;
  else if (ws_size >= PER_B_BYTES + WB_BYTES) bcnt = 1;
  else return;
  int passes = 4 / bcnt;

  float* ws = (float*)d_ws;
  float* wsW = ws + (size_t)bcnt * PER_B;
  kprepw<<<dim3(27), 256, 0, stream>>>(pw, wsW);
  for (int p = 0; p < passes; ++p) {
    int b0 = p * bcnt;
    kxz   <<<dim3(256, bcnt), 256, 0, stream>>>(x, wip, ws, b0);
    k2prep<<<dim3(256, bcnt), 256, 0, stream>>>(cwf, cbf, xpf, dtwf, dtbf,
                                                cwb, cbb, xpb, dtwb, dtbb, ws);
    kscanA<<<dim3(1024, bcnt), 256, 0, stream>>>(Alf, Alb, ws);
    kscanB<<<dim3(64, bcnt), 64, 0, stream>>>(ws);
    kscanC<<<dim3(1024, bcnt), 256, 0, stream>>>(Alf, Df, Alb, Db, ws);
    koutg <<<dim3(128, bcnt), 256, 0, stream>>>(wout, ws);
    kconv3<<<dim3(128, bcnt), 512, 0, stream>>>(pb, nw, nb, x, (float*)d_out,
                                                (const u16*)wsW, ws, b0);
  }
}

// Round 6
// 260.650 us; speedup vs baseline: 1.0483x; 1.0483x over previous
//
#include <hip/hip_runtime.h>

// ---------------------------------------------------------------------------
// Bidirectional Mamba block, MI355X. Round 26:
//  - kconv3: R25 falsified occupancy theory (occ x3, slower; VALU 6%). Real
//    constraint: serialized cross-XCD weight loads (L3 latency) under a
//    32-VGPR regalloc. Fixes: (1) 8 XCD-local Wbf replicas, block picks
//    blockIdx.x&7 -> L2-hit A-loads; (2) wave = 16co x 64l -> one A-load
//    feeds 4 MFMAs (weight traffic 220->55 MB) + 4 indep acc chains;
//    (3) __launch_bounds__(256,1) for load-pipelining registers.
//  - knorm fused in kconv3 (R24); koutg/x_dbl/conv on MFMA (R21-24).
// Shapes: B=4, C=64, D=128, L=4096 (l = h*256 + w*16 + t), N=16, R=8.
// ---------------------------------------------------------------------------

#define NL 4096

typedef unsigned short u16;
typedef unsigned int u32;
typedef __attribute__((ext_vector_type(8))) short bf16x8;
typedef __attribute__((ext_vector_type(4))) float f32x4;

__device__ __forceinline__ float siluf_(float x) {
  return x * __builtin_amdgcn_rcpf(1.f + __expf(-x));
}
__device__ __forceinline__ float softplusf_(float x) {
  return (x > 20.f) ? x : __logf(1.f + __expf(x));
}
__device__ __forceinline__ u16 f2bf(float f) {
  u32 u = __float_as_uint(f);
  u += 0x7fffu + ((u >> 16) & 1u);
  return (u16)(u >> 16);
}
__device__ __forceinline__ float bflo(u32 v) { return __uint_as_float(v << 16); }
__device__ __forceinline__ float bfhi(u32 v) { return __uint_as_float(v & 0xFFFF0000u); }

// Sum over the 16-lane DPP row via rotations 1,2,4,8 (VALU pipe, no DS).
__device__ __forceinline__ float rowsum16_(float p) {
  int q;
  q = __builtin_amdgcn_mov_dpp(__float_as_int(p), 0x121, 0xf, 0xf, false);
  p += __int_as_float(q);
  q = __builtin_amdgcn_mov_dpp(__float_as_int(p), 0x122, 0xf, 0xf, false);
  p += __int_as_float(q);
  q = __builtin_amdgcn_mov_dpp(__float_as_int(p), 0x124, 0xf, 0xf, false);
  p += __int_as_float(q);
  q = __builtin_amdgcn_mov_dpp(__float_as_int(p), 0x128, 0xf, 0xf, false);
  p += __int_as_float(q);
  return p;
}

// Per-b slab offsets (fp32 elements; bf16 regions use u16 views at same base)
#define OXZ  0u          // xz [256][4096] fp32
#define OUCF 1048576u    // ucf [128][4096] bf16 (u16 view)
#define OUCB 1572864u    // ucb [128][4096] bf16 (flipped coords)
#define ODLF 2424832u    // dlf [128][4096] bf16
#define ODLB 2949120u    // dlb [128][4096] bf16 (flipped coords)
#define OYF  3473408u    // yf [128][4096] fp32
#define OYB  3997696u    // yb [128][4096] fp32 (flipped coords)
#define OO   4521984u    // scan scratch: P [262144] S [262144] fp32
#define OO2  5046272u    // bct bf16 until kscanC; then o2 [4096][64] fp32
#define PER_B 5570560u
// Wbf8 [8 xcd][27][64][64] bf16 lives at ws + bcnt*PER_B

#define NCH 64   // scan chunks
#define CL  64   // chunk length
#define WB1 110592u  // u16 elems per Wbf copy (27*64*64)

// 1. xz[e,l] = sum_c in_proj_w[e,c] * seq[c,l].
__global__ __launch_bounds__(256) void kxz(
    const float* __restrict__ x, const float* __restrict__ wip,
    float* __restrict__ ws, int b0) {
  int bi = blockIdx.y, gb = b0 + bi;
  float* s = ws + (size_t)bi * PER_B;
  int bid = blockIdx.x;
  int h = bid >> 4, w = bid & 15;
  int tid = threadIdx.x;
  __shared__ float xs[64][16];
  for (int i = tid; i < 1024; i += 256) {
    int c = i >> 4, t = i & 15;
    xs[c][t] = x[(size_t)(gb * 64 + c) * NL + t * 256 + h * 16 + w];
  }
  __syncthreads();
  int e = tid;
  float acc[16];
#pragma unroll
  for (int t = 0; t < 16; ++t) acc[t] = 0.f;
  for (int c = 0; c < 64; ++c) {
    float wv = wip[e * 64 + c];
#pragma unroll
    for (int t = 0; t < 16; ++t) acc[t] = fmaf(wv, xs[c][t], acc[t]);
  }
  float4* dst = (float4*)(s + OXZ + (size_t)e * NL + h * 256 + w * 16);
#pragma unroll
  for (int q = 0; q < 4; ++q)
    dst[q] = make_float4(acc[q * 4], acc[q * 4 + 1], acc[q * 4 + 2], acc[q * 4 + 3]);
}

// 2. Fused prep per (bi, dir, 32-l tile): dwconv+silu, x_dbl via MFMA, delta,
// bct. Grid x = 256 (lt 128 x dir 2).
__global__ __launch_bounds__(256) void k2prep(
    const float* __restrict__ cwf, const float* __restrict__ cbf,
    const float* __restrict__ xpf, const float* __restrict__ dtwf,
    const float* __restrict__ dtbf,
    const float* __restrict__ cwb, const float* __restrict__ cbb,
    const float* __restrict__ xpb, const float* __restrict__ dtwb,
    const float* __restrict__ dtbb,
    float* __restrict__ ws) {
  int bi = blockIdx.y;
  float* s = ws + (size_t)bi * PER_B;
  int bx = blockIdx.x;
  int lt = bx >> 1, dir = bx & 1;
  int l0 = lt * 32;
  int lout0 = dir ? (127 - lt) * 32 : l0;   // output base (flipped for bwd)
  int tid = threadIdx.x;

  __shared__ float pool[128 * 40];   // X[128][40] during dwconv; xds after
  __shared__ u16 uct[32][136];       // uc transposed bf16 (d-contig, 16B rows)
  float (*X)[40] = (float(*)[40])pool;

  for (int i = tid; i < 128 * 38; i += 256) {
    int d = i / 38, j = i - d * 38;
    int l = l0 - 3 + j;
    X[d][j] = (l >= 0 && l < NL) ? s[OXZ + (size_t)d * NL + l] : 0.f;
  }
  __syncthreads();

  const float* cw = dir ? cwb : cwf;
  const float* cb = dir ? cbb : cbf;
  u16* ucg = (u16*)(s + (dir ? OUCB : OUCF));
  for (int i = tid; i < 128 * 32; i += 256) {
    int d = i >> 5, li = i & 31;
    float a = cb[d];
    if (dir == 0) {
#pragma unroll
      for (int k = 0; k < 4; ++k) a = fmaf(cw[d * 4 + k], X[d][li + k], a);
    } else {
#pragma unroll
      for (int k = 0; k < 4; ++k) a = fmaf(cw[d * 4 + k], X[d][37 - li - k], a);
    }
    a = siluf_(a);
    u16 ab = f2bf(a);
    uct[li][d] = ab;
    ucg[(size_t)d * NL + lout0 + li] = ab;
  }
  __syncthreads();  // X dead; pool becomes xds [40][33]

  // x_dbl via MFMA 16x16x32: D[e 48][l 32], K=128. Units (et,lt2) = 6 over
  // 4 waves (waves 0,1 take two units).
  float* xds = pool;
  {
    int wid = tid >> 6, lane = tid & 63;
    int n16 = lane & 15, kg = lane >> 4;
    const float* xp = dir ? xpb : xpf;
#pragma unroll
    for (int rep = 0; rep < 2; ++rep) {
      int id = wid + rep * 4;
      if (id < 6) {
        int et = id >> 1, lt2 = id & 1;
        f32x4 acc = {};
#pragma unroll
        for (int ks = 0; ks < 4; ++ks) {
          bf16x8 bfrag = *(const bf16x8*)&uct[lt2 * 16 + n16][ks * 32 + kg * 8];
          int e = et * 16 + n16;
          int ec = (e < 40) ? e : 39;        // clamp addr; rows >=40 discarded
          const float* pa = xp + ec * 128 + ks * 32 + kg * 8;
          float4 a0 = *(const float4*)pa;
          float4 a1 = *(const float4*)(pa + 4);
          bf16x8 af;
          af[0] = (short)f2bf(a0.x); af[1] = (short)f2bf(a0.y);
          af[2] = (short)f2bf(a0.z); af[3] = (short)f2bf(a0.w);
          af[4] = (short)f2bf(a1.x); af[5] = (short)f2bf(a1.y);
          af[6] = (short)f2bf(a1.z); af[7] = (short)f2bf(a1.w);
          acc = __builtin_amdgcn_mfma_f32_16x16x32_bf16(af, bfrag, acc, 0, 0, 0);
        }
        // D layout: col = lane&15 (l), row = kg*4 + rg (e within 16-tile)
#pragma unroll
        for (int rg = 0; rg < 4; ++rg) {
          int e = et * 16 + kg * 4 + rg;
          if (e < 40) xds[e * 33 + lt2 * 16 + n16] = acc[rg];
        }
      }
    }
  }
  __syncthreads();

  const float* dtw = dir ? dtwb : dtwf;
  const float* dtb = dir ? dtbb : dtbf;
  u16* dlg = (u16*)(s + (dir ? ODLB : ODLF));
  for (int i = tid; i < 128 * 32; i += 256) {
    int d = i >> 5, li = i & 31;
    float pre = dtb[d];
#pragma unroll
    for (int r = 0; r < 8; ++r)
      pre = fmaf(dtw[d * 8 + r], xds[r * 33 + li], pre);
    dlg[(size_t)d * NL + lout0 + li] = f2bf(softplusf_(pre));
  }
  u16* bctp = (u16*)(s + OO2);
  for (int i = tid; i < 32 * 32; i += 256) {
    int li = i >> 5, k = i & 31;
    bctp[((size_t)dir * 4096 + lout0 + li) * 32 + k] = f2bf(xds[(8 + k) * 33 + li]);
  }
}

// 5a. Phase A: 16 d-rows/block; chunk bct (bf16) staged to fp32 LDS;
// ushort8 dl/uc loads = 8 steps per load pair.
__global__ __launch_bounds__(256) void kscanA(
    const float* __restrict__ Alf, const float* __restrict__ Alb,
    float* __restrict__ ws) {
  int bi = blockIdx.y;
  float* s = ws + (size_t)bi * PER_B;
  int xid = blockIdx.x;
  int chunk = xid >> 4, dir = (xid >> 3) & 1, d8 = xid & 7;
  int tid = threadIdx.x;
  int wv = tid >> 6, lane = tid & 63;
  int n = lane & 15, g = lane >> 4;
  int d = d8 * 16 + wv * 4 + g;
  int l0 = chunk * CL;
  __shared__ float bl[CL * 32];
  {
    const u16* bctp = (const u16*)(s + OO2) + ((size_t)dir * 4096 + l0) * 32;
    for (int i = tid; i < CL * 32; i += 256)
      bl[i] = __uint_as_float(((u32)bctp[i]) << 16);
  }
  __syncthreads();
  const u16* ucp = (const u16*)(s + (dir ? OUCB : OUCF)) + (size_t)d * NL + l0;
  const u16* dlp = (const u16*)(s + (dir ? ODLB : ODLF)) + (size_t)d * NL + l0;
  float A = -__expf((dir ? Alb : Alf)[d * 16 + n]);
  float P = 1.f, S = 0.f;
  for (int i0 = 0; i0 < CL; i0 += 8) {
    uint4 dq = *(const uint4*)(dlp + i0);
    uint4 uq = *(const uint4*)(ucp + i0);
    float dv[8] = {bflo(dq.x), bfhi(dq.x), bflo(dq.y), bfhi(dq.y),
                   bflo(dq.z), bfhi(dq.z), bflo(dq.w), bfhi(dq.w)};
    float uv[8] = {bflo(uq.x), bfhi(uq.x), bflo(uq.y), bfhi(uq.y),
                   bflo(uq.z), bfhi(uq.z), bflo(uq.w), bfhi(uq.w)};
#pragma unroll
    for (int j = 0; j < 8; ++j) {
      float dA = __expf(dv[j] * A);
      S = fmaf(dA, S, dv[j] * bl[(i0 + j) * 32 + n] * uv[j]);
      P *= dA;
    }
  }
  size_t cidx = ((size_t)(chunk * 2 + dir) * 128 + d) * 16 + n;
  s[OO + cidx] = P;
  s[OO + 262144u + cidx] = S;
}

// 5b. Phase B: carry combine.
__global__ __launch_bounds__(64) void kscanB(float* __restrict__ ws) {
  int bi = blockIdx.y;
  float* s = ws + (size_t)bi * PER_B;
  int dir = blockIdx.x >> 5, dblk = blockIdx.x & 31;
  int tid = threadIdx.x;
  size_t base = (size_t)dir * 2048 + dblk * 64 + tid;
  float carry = 0.f;
#pragma unroll 4
  for (int c = 0; c < NCH; ++c) {
    size_t idx = (size_t)c * 4096 + base;
    float pv = s[OO + idx], sv = s[OO + 262144u + idx];
    s[OO + 262144u + idx] = carry;
    carry = fmaf(pv, carry, sv);
  }
}

// 5c. Phase C: seeded re-scan; bf16 inputs; DPP row-sum; ps[16][65] staging.
__global__ __launch_bounds__(256) void kscanC(
    const float* __restrict__ Alf, const float* __restrict__ Df,
    const float* __restrict__ Alb, const float* __restrict__ Db,
    float* __restrict__ ws) {
  int bi = blockIdx.y;
  float* s = ws + (size_t)bi * PER_B;
  int xid = blockIdx.x;
  int chunk = xid >> 4, dir = (xid >> 3) & 1, d8 = xid & 7;
  int tid = threadIdx.x;
  int wv = tid >> 6, lane = tid & 63;
  int n = lane & 15, g = lane >> 4;
  int d = d8 * 16 + wv * 4 + g;
  int l0 = chunk * CL;
  __shared__ float bl[CL * 32];
  __shared__ float ps[16][65];
  {
    const u16* bctp = (const u16*)(s + OO2) + ((size_t)dir * 4096 + l0) * 32;
    for (int i = tid; i < CL * 32; i += 256)
      bl[i] = __uint_as_float(((u32)bctp[i]) << 16);
  }
  __syncthreads();
  const u16* ucp = (const u16*)(s + (dir ? OUCB : OUCF)) + (size_t)d * NL + l0;
  const u16* dlp = (const u16*)(s + (dir ? ODLB : ODLF)) + (size_t)d * NL + l0;
  float* ybase = s + (dir ? OYB : OYF);
  float A = -__expf((dir ? Alb : Alf)[d * 16 + n]);
  float Dv = (dir ? Db : Df)[d];
  size_t cidx = ((size_t)(chunk * 2 + dir) * 128 + d) * 16 + n;
  float h = s[OO + 262144u + cidx];
  int prow = wv * 4 + g;
  for (int i0 = 0; i0 < CL; i0 += 8) {
    uint4 dq = *(const uint4*)(dlp + i0);
    uint4 uq = *(const uint4*)(ucp + i0);
    float dv[8] = {bflo(dq.x), bfhi(dq.x), bflo(dq.y), bfhi(dq.y),
                   bflo(dq.z), bfhi(dq.z), bflo(dq.w), bfhi(dq.w)};
    float uv[8] = {bflo(uq.x), bfhi(uq.x), bflo(uq.y), bfhi(uq.y),
                   bflo(uq.z), bfhi(uq.z), bflo(uq.w), bfhi(uq.w)};
#pragma unroll
    for (int j = 0; j < 8; ++j) {
      int i = i0 + j;
      float dA = __expf(dv[j] * A);
      h = fmaf(dA, h, dv[j] * bl[i * 32 + n] * uv[j]);
      float p = rowsum16_(h * bl[i * 32 + 16 + n]);
      if (n == 0) ps[prow][i] = fmaf(uv[j], Dv, p);
    }
  }
  __syncthreads();
  for (int i = tid; i < 16 * CL; i += 256) {
    int row = i >> 6, col = i & 63;
    ybase[(size_t)(d8 * 16 + row) * NL + l0 + col] = ps[row][col];
  }
}

// 6. Fused gate + out-proj via MFMA. Block = 32-l tile.
// Gate: otb[l 32][d 128 pad 136] bf16 (transposed, 16B rows). Out-proj:
// D[c 64][l 32], K=128; wave ct handles both l2 tiles; float4 stores.
__global__ __launch_bounds__(256) void koutg(
    const float* __restrict__ wout, float* __restrict__ ws) {
  int bi = blockIdx.y;
  float* s = ws + (size_t)bi * PER_B;
  int lt = blockIdx.x;
  int l0 = lt * 32;
  int tid = threadIdx.x;
  __shared__ u16 otb[32][136];
  for (int i = tid; i < 128 * 32; i += 256) {
    int d = i >> 5, li = i & 31;
    int l = l0 + li;
    float z = s[OXZ + (size_t)(128 + d) * NL + l];
    float v = s[OYF + (size_t)d * NL + l] + s[OYB + (size_t)d * NL + (NL - 1 - l)];
    otb[li][d] = f2bf(v * siluf_(z));
  }
  __syncthreads();
  int wid = tid >> 6, lane = tid & 63;
  int n16 = lane & 15, kg = lane >> 4;
  f32x4 acc[2] = {};   // [l2 tile]
  const float* wr = wout + (size_t)(wid * 16 + n16) * 128 + kg * 8;
#pragma unroll
  for (int ks = 0; ks < 4; ++ks) {
    const float* pa = wr + ks * 32;
    float4 a0 = *(const float4*)pa;
    float4 a1 = *(const float4*)(pa + 4);
    bf16x8 af;
    af[0] = (short)f2bf(a0.x); af[1] = (short)f2bf(a0.y);
    af[2] = (short)f2bf(a0.z); af[3] = (short)f2bf(a0.w);
    af[4] = (short)f2bf(a1.x); af[5] = (short)f2bf(a1.y);
    af[6] = (short)f2bf(a1.z); af[7] = (short)f2bf(a1.w);
    bf16x8 b0 = *(const bf16x8*)&otb[n16][ks * 32 + kg * 8];
    bf16x8 b1 = *(const bf16x8*)&otb[16 + n16][ks * 32 + kg * 8];
    acc[0] = __builtin_amdgcn_mfma_f32_16x16x32_bf16(af, b0, acc[0], 0, 0, 0);
    acc[1] = __builtin_amdgcn_mfma_f32_16x16x32_bf16(af, b1, acc[1], 0, 0, 0);
  }
  // D: col = lane&15 (l), row = kg*4+rg (c in 16-tile); rg = consecutive c.
#pragma unroll
  for (int l2 = 0; l2 < 2; ++l2) {
    float4 st = make_float4(acc[l2][0], acc[l2][1], acc[l2][2], acc[l2][3]);
    *(float4*)&s[OO2 + (size_t)(l0 + l2 * 16 + n16) * 64 + wid * 16 + kg * 4] = st;
  }
}

// 6.5. Weight prep: Wbf8[xcd 8][27][co 64][ci 64] bf16 at ws + bcnt*PER_B.
// 8 replicas so each XCD's L2 caches its own copy (kconv3 picks bx&7).
__global__ __launch_bounds__(256) void kprepw(
    const float* __restrict__ pw, float* __restrict__ wdst) {
  int off = blockIdx.x;
  u16* wb = (u16*)wdst;
  int tid = threadIdx.x;
  for (int i = tid; i < 4096; i += 256) {
    int co = i >> 6, ci = i & 63;
    u16 v = f2bf(pw[(size_t)(co * 64 + ci) * 27 + off]);
#pragma unroll
    for (int xc = 0; xc < 8; ++xc)
      wb[(size_t)xc * WB1 + off * 4096 + i] = v;
  }
}

// 7. conv3d (bf16 implicit GEMM on MFMA) + FUSED 1x1x1 norm mix.
// Block tile [64 co][64 l] = one t-plane x 4 h-rows; grid = t(16) x hq(4).
// 256 thr / 4 waves; wave cq = 16co x 64l: per (tap,st): 1 A-load (16B,
// XCD-local Wbf replica, L2-hit) + 4 ds_read_b128 + 4 MFMA (4 indep chains).
// LDS: halo Xs[tt 3][hh 6][ww 18][ci 64 pad 72] bf16 (46.6 KB); after MFMA
// aliased as cx[ci 64][lp 64 pad 65] fp32, then 1x1x1 norm mix -> global.
__global__ __launch_bounds__(256, 1) void kconv3(
    const float* __restrict__ pb, const float* __restrict__ nw,
    const float* __restrict__ nb, const float* __restrict__ xin,
    float* __restrict__ out, const u16* __restrict__ wb,
    float* __restrict__ ws, int b0) {
  int bi = blockIdx.y, gb = b0 + bi;
  float* s = ws + (size_t)bi * PER_B;
  int bx = blockIdx.x;
  int t = bx >> 2, hq = bx & 3;
  int h0 = hq * 4;
  int tid = threadIdx.x;
  const float* xr = s + OO2;              // o2 in c-major reshape view

  __shared__ u16 Xs[3 * 6 * 18 * 72];     // 46656 B; later aliased as cx
  float* cx = (float*)Xs;                 // cx[64][65] = 16640 B
  // zero (covers t/h/w halo padding)
  {
    u32* xz32 = (u32*)Xs;
    for (int i = tid; i < 3 * 6 * 18 * 72 / 2; i += 256) xz32[i] = 0u;
  }
  __syncthreads();
  // stage valid rows, transposed to ci-contiguous bf16
  {
    int ci = tid >> 2, wq = tid & 3;
    for (int row = 0; row < 18; ++row) {
      int tt = row / 6, hh = row - tt * 6;
      int ts = t + tt - 1, hs = h0 + hh - 1;
      if (ts < 0 || ts > 15 || hs < 0 || hs > 15) continue;
      float4 v = *(const float4*)(xr + (size_t)ci * NL + ts * 256 + hs * 16 + wq * 4);
      int rb = (tt * 6 + hh) * 18 + 1 + wq * 4;
      Xs[(rb + 0) * 72 + ci] = f2bf(v.x);
      Xs[(rb + 1) * 72 + ci] = f2bf(v.y);
      Xs[(rb + 2) * 72 + ci] = f2bf(v.z);
      Xs[(rb + 3) * 72 + ci] = f2bf(v.w);
    }
  }
  __syncthreads();

  int wid = tid >> 6, lane = tid & 63;
  int cq = wid;                          // 16-co subtile per wave
  int n16 = lane & 15, kg = lane >> 4;   // k-group 0..3 (8 ci each)
  f32x4 acc[4] = {};                     // 4 l2 (h-row) chains

  // A: XCD-local replica; lane row co = cq*16 + n16, k = kg*8 + st*32 + j
  const u16* wbA = wb + (size_t)(bx & 7) * WB1 +
                   (size_t)(cq * 16 + n16) * 64 + kg * 8;
#pragma unroll
  for (int kt = 0; kt < 3; ++kt)
#pragma unroll
    for (int kh = 0; kh < 3; ++kh) {
#pragma unroll
      for (int kw = 0; kw < 3; ++kw) {
        int off = (kt * 3 + kh) * 3 + kw;
        const u16* pa = wbA + off * 4096;
#pragma unroll
        for (int st = 0; st < 2; ++st) {
          int kb = st * 32;
          bf16x8 a0 = *(const bf16x8*)(pa + kb);
#pragma unroll
          for (int l2 = 0; l2 < 4; ++l2) {
            int r = (kt * 6 + l2 + kh) * 18 + n16 + kw;
            bf16x8 b0 = *(const bf16x8*)(&Xs[r * 72 + kb + kg * 8]);
            acc[l2] = __builtin_amdgcn_mfma_f32_16x16x32_bf16(a0, b0, acc[l2], 0, 0, 0);
          }
        }
      }
    }
  __syncthreads();  // all Xs reads done; safe to overwrite with cx

  // cx[co][lp] = conv + bias + residual.
  // C/D layout: col = lane&15 (w), row = kg*4 + rg (co within 16-subtile)
#pragma unroll
  for (int l2 = 0; l2 < 4; ++l2) {
    int lp = l2 * 16 + n16;
    int lg = t * 256 + (h0 + l2) * 16 + n16;
#pragma unroll
    for (int rg = 0; rg < 4; ++rg) {
      int co = cq * 16 + kg * 4 + rg;
      cx[co * 65 + lp] = acc[l2][rg] + pb[co] +
                         xin[(size_t)(gb * 64 + co) * NL + lg];
    }
  }
  __syncthreads();

  // 1x1x1 norm mix: out[co2][lp] = nb + sum_ci nw[co2,ci] * cx[ci][lp]
  {
    int co2 = tid >> 2, pq = tid & 3;
    float mac[16];
#pragma unroll
    for (int j = 0; j < 16; ++j) mac[j] = 0.f;
    for (int ci = 0; ci < 64; ci += 4) {
      float4 w4 = *(const float4*)&nw[co2 * 64 + ci];
      float wv[4] = {w4.x, w4.y, w4.z, w4.w};
#pragma unroll
      for (int cc = 0; cc < 4; ++cc) {
        const float* row = &cx[(ci + cc) * 65 + pq * 16];
        float4 a = *(const float4*)&row[0];
        float4 b = *(const float4*)&row[4];
        float4 c = *(const float4*)&row[8];
        float4 e = *(const float4*)&row[12];
        mac[0] = fmaf(wv[cc], a.x, mac[0]);   mac[1] = fmaf(wv[cc], a.y, mac[1]);
        mac[2] = fmaf(wv[cc], a.z, mac[2]);   mac[3] = fmaf(wv[cc], a.w, mac[3]);
        mac[4] = fmaf(wv[cc], b.x, mac[4]);   mac[5] = fmaf(wv[cc], b.y, mac[5]);
        mac[6] = fmaf(wv[cc], b.z, mac[6]);   mac[7] = fmaf(wv[cc], b.w, mac[7]);
        mac[8] = fmaf(wv[cc], c.x, mac[8]);   mac[9] = fmaf(wv[cc], c.y, mac[9]);
        mac[10] = fmaf(wv[cc], c.z, mac[10]); mac[11] = fmaf(wv[cc], c.w, mac[11]);
        mac[12] = fmaf(wv[cc], e.x, mac[12]); mac[13] = fmaf(wv[cc], e.y, mac[13]);
        mac[14] = fmaf(wv[cc], e.z, mac[14]); mac[15] = fmaf(wv[cc], e.w, mac[15]);
      }
    }
    float bias = nb[co2];
    float4* dst = (float4*)(out + (size_t)(gb * 64 + co2) * NL +
                            t * 256 + h0 * 16 + pq * 16);
#pragma unroll
    for (int q = 0; q < 4; ++q)
      dst[q] = make_float4(mac[q * 4] + bias, mac[q * 4 + 1] + bias,
                           mac[q * 4 + 2] + bias, mac[q * 4 + 3] + bias);
  }
}

// ---------------------------------------------------------------------------
extern "C" void kernel_launch(void* const* d_in, const int* in_sizes, int n_in,
                              void* d_out, int out_size, void* d_ws, size_t ws_size,
                              hipStream_t stream) {
  const float* x    = (const float*)d_in[0];
  const float* wip  = (const float*)d_in[1];
  const float* cwf  = (const float*)d_in[2];
  const float* cbf  = (const float*)d_in[3];
  const float* xpf  = (const float*)d_in[4];
  const float* dtwf = (const float*)d_in[5];
  const float* dtbf = (const float*)d_in[6];
  const float* Alf  = (const float*)d_in[7];
  const float* Df   = (const float*)d_in[8];
  const float* cwb  = (const float*)d_in[9];
  const float* cbb  = (const float*)d_in[10];
  const float* xpb  = (const float*)d_in[11];
  const float* dtwb = (const float*)d_in[12];
  const float* dtbb = (const float*)d_in[13];
  const float* Alb  = (const float*)d_in[14];
  const float* Db   = (const float*)d_in[15];
  const float* wout = (const float*)d_in[16];
  const float* pw   = (const float*)d_in[17];
  const float* pb   = (const float*)d_in[18];
  const float* nw   = (const float*)d_in[19];
  const float* nb   = (const float*)d_in[20];

  const size_t PER_B_BYTES = (size_t)PER_B * 4;  // 22,282,240 per batch slab
  const size_t WB_BYTES = 8u * WB1 * 2u;         // 1,769,472 (8 Wbf replicas)
  int bcnt;
  if (ws_size >= 4 * PER_B_BYTES + WB_BYTES) bcnt = 4;
  else if (ws_size >= PER_B_BYTES + WB_BYTES) bcnt = 1;
  else return;
  int passes = 4 / bcnt;

  float* ws = (float*)d_ws;
  float* wsW = ws + (size_t)bcnt * PER_B;
  kprepw<<<dim3(27), 256, 0, stream>>>(pw, wsW);
  for (int p = 0; p < passes; ++p) {
    int b0 = p * bcnt;
    kxz   <<<dim3(256, bcnt), 256, 0, stream>>>(x, wip, ws, b0);
    k2prep<<<dim3(256, bcnt), 256, 0, stream>>>(cwf, cbf, xpf, dtwf, dtbf,
                                                cwb, cbb, xpb, dtwb, dtbb, ws);
    kscanA<<<dim3(1024, bcnt), 256, 0, stream>>>(Alf, Alb, ws);
    kscanB<<<dim3(64, bcnt), 64, 0, stream>>>(ws);
    kscanC<<<dim3(1024, bcnt), 256, 0, stream>>>(Alf, Df, Alb, Db, ws);
    koutg <<<dim3(128, bcnt), 256, 0, stream>>>(wout, ws);
    kconv3<<<dim3(64, bcnt), 256, 0, stream>>>(pb, nw, nb, x, (float*)d_out,
                                               (const u16*)wsW, ws, b0);
  }
}

// Round 7
// 257.841 us; speedup vs baseline: 1.0597x; 1.0109x over previous
//
#include <hip/hip_runtime.h>

// ---------------------------------------------------------------------------
// Bidirectional Mamba block, MI355X. Round 27:
//  - kconv3: R25 geometry + R26 fixes together. 32-l tiles (t16 x hq8, 512
//    blocks = 2/CU, 8 waves/CU) with XCD-local Wbf replicas, 2-MFMA-per-A-load
//    reuse, and __launch_bounds__(256,2) (128 VGPR cap - R25's real failure
//    was the 32-VGPR regalloc from plain launch_bounds(512)). LDS 31.1 KB.
//  - kscanB ELIMINATED: kscanC self-seeds by folding prior chunks' P/S pairs
//    (<=63 independent L2-hit loads + fma chain) - one fewer launch+drain.
//  - kscanA stages only the B-half of bct (it never reads the C-half).
// Shapes: B=4, C=64, D=128, L=4096 (l = h*256 + w*16 + t), N=16, R=8.
// ---------------------------------------------------------------------------

#define NL 4096

typedef unsigned short u16;
typedef unsigned int u32;
typedef __attribute__((ext_vector_type(8))) short bf16x8;
typedef __attribute__((ext_vector_type(4))) float f32x4;

__device__ __forceinline__ float siluf_(float x) {
  return x * __builtin_amdgcn_rcpf(1.f + __expf(-x));
}
__device__ __forceinline__ float softplusf_(float x) {
  return (x > 20.f) ? x : __logf(1.f + __expf(x));
}
__device__ __forceinline__ u16 f2bf(float f) {
  u32 u = __float_as_uint(f);
  u += 0x7fffu + ((u >> 16) & 1u);
  return (u16)(u >> 16);
}
__device__ __forceinline__ float bflo(u32 v) { return __uint_as_float(v << 16); }
__device__ __forceinline__ float bfhi(u32 v) { return __uint_as_float(v & 0xFFFF0000u); }

// Sum over the 16-lane DPP row via rotations 1,2,4,8 (VALU pipe, no DS).
__device__ __forceinline__ float rowsum16_(float p) {
  int q;
  q = __builtin_amdgcn_mov_dpp(__float_as_int(p), 0x121, 0xf, 0xf, false);
  p += __int_as_float(q);
  q = __builtin_amdgcn_mov_dpp(__float_as_int(p), 0x122, 0xf, 0xf, false);
  p += __int_as_float(q);
  q = __builtin_amdgcn_mov_dpp(__float_as_int(p), 0x124, 0xf, 0xf, false);
  p += __int_as_float(q);
  q = __builtin_amdgcn_mov_dpp(__float_as_int(p), 0x128, 0xf, 0xf, false);
  p += __int_as_float(q);
  return p;
}

// Per-b slab offsets (fp32 elements; bf16 regions use u16 views at same base)
#define OXZ  0u          // xz [256][4096] fp32
#define OUCF 1048576u    // ucf [128][4096] bf16 (u16 view)
#define OUCB 1572864u    // ucb [128][4096] bf16 (flipped coords)
#define ODLF 2424832u    // dlf [128][4096] bf16
#define ODLB 2949120u    // dlb [128][4096] bf16 (flipped coords)
#define OYF  3473408u    // yf [128][4096] fp32
#define OYB  3997696u    // yb [128][4096] fp32 (flipped coords)
#define OO   4521984u    // scan scratch: P [262144] S [262144] fp32
#define OO2  5046272u    // bct bf16 until kscanC; then o2 [4096][64] fp32
#define PER_B 5570560u
// Wbf8 [8 xcd][27][64][64] bf16 lives at ws + bcnt*PER_B

#define NCH 64   // scan chunks
#define CL  64   // chunk length
#define WB1 110592u  // u16 elems per Wbf copy (27*64*64)

// 1. xz[e,l] = sum_c in_proj_w[e,c] * seq[c,l].
__global__ __launch_bounds__(256) void kxz(
    const float* __restrict__ x, const float* __restrict__ wip,
    float* __restrict__ ws, int b0) {
  int bi = blockIdx.y, gb = b0 + bi;
  float* s = ws + (size_t)bi * PER_B;
  int bid = blockIdx.x;
  int h = bid >> 4, w = bid & 15;
  int tid = threadIdx.x;
  __shared__ float xs[64][16];
  for (int i = tid; i < 1024; i += 256) {
    int c = i >> 4, t = i & 15;
    xs[c][t] = x[(size_t)(gb * 64 + c) * NL + t * 256 + h * 16 + w];
  }
  __syncthreads();
  int e = tid;
  float acc[16];
#pragma unroll
  for (int t = 0; t < 16; ++t) acc[t] = 0.f;
  for (int c = 0; c < 64; ++c) {
    float wv = wip[e * 64 + c];
#pragma unroll
    for (int t = 0; t < 16; ++t) acc[t] = fmaf(wv, xs[c][t], acc[t]);
  }
  float4* dst = (float4*)(s + OXZ + (size_t)e * NL + h * 256 + w * 16);
#pragma unroll
  for (int q = 0; q < 4; ++q)
    dst[q] = make_float4(acc[q * 4], acc[q * 4 + 1], acc[q * 4 + 2], acc[q * 4 + 3]);
}

// 2. Fused prep per (bi, dir, 32-l tile): dwconv+silu, x_dbl via MFMA, delta,
// bct. Grid x = 256 (lt 128 x dir 2).
__global__ __launch_bounds__(256) void k2prep(
    const float* __restrict__ cwf, const float* __restrict__ cbf,
    const float* __restrict__ xpf, const float* __restrict__ dtwf,
    const float* __restrict__ dtbf,
    const float* __restrict__ cwb, const float* __restrict__ cbb,
    const float* __restrict__ xpb, const float* __restrict__ dtwb,
    const float* __restrict__ dtbb,
    float* __restrict__ ws) {
  int bi = blockIdx.y;
  float* s = ws + (size_t)bi * PER_B;
  int bx = blockIdx.x;
  int lt = bx >> 1, dir = bx & 1;
  int l0 = lt * 32;
  int lout0 = dir ? (127 - lt) * 32 : l0;   // output base (flipped for bwd)
  int tid = threadIdx.x;

  __shared__ float pool[128 * 40];   // X[128][40] during dwconv; xds after
  __shared__ u16 uct[32][136];       // uc transposed bf16 (d-contig, 16B rows)
  float (*X)[40] = (float(*)[40])pool;

  for (int i = tid; i < 128 * 38; i += 256) {
    int d = i / 38, j = i - d * 38;
    int l = l0 - 3 + j;
    X[d][j] = (l >= 0 && l < NL) ? s[OXZ + (size_t)d * NL + l] : 0.f;
  }
  __syncthreads();

  const float* cw = dir ? cwb : cwf;
  const float* cb = dir ? cbb : cbf;
  u16* ucg = (u16*)(s + (dir ? OUCB : OUCF));
  for (int i = tid; i < 128 * 32; i += 256) {
    int d = i >> 5, li = i & 31;
    float a = cb[d];
    if (dir == 0) {
#pragma unroll
      for (int k = 0; k < 4; ++k) a = fmaf(cw[d * 4 + k], X[d][li + k], a);
    } else {
#pragma unroll
      for (int k = 0; k < 4; ++k) a = fmaf(cw[d * 4 + k], X[d][37 - li - k], a);
    }
    a = siluf_(a);
    u16 ab = f2bf(a);
    uct[li][d] = ab;
    ucg[(size_t)d * NL + lout0 + li] = ab;
  }
  __syncthreads();  // X dead; pool becomes xds [40][33]

  // x_dbl via MFMA 16x16x32: D[e 48][l 32], K=128. Units (et,lt2) = 6 over
  // 4 waves (waves 0,1 take two units).
  float* xds = pool;
  {
    int wid = tid >> 6, lane = tid & 63;
    int n16 = lane & 15, kg = lane >> 4;
    const float* xp = dir ? xpb : xpf;
#pragma unroll
    for (int rep = 0; rep < 2; ++rep) {
      int id = wid + rep * 4;
      if (id < 6) {
        int et = id >> 1, lt2 = id & 1;
        f32x4 acc = {};
#pragma unroll
        for (int ks = 0; ks < 4; ++ks) {
          bf16x8 bfrag = *(const bf16x8*)&uct[lt2 * 16 + n16][ks * 32 + kg * 8];
          int e = et * 16 + n16;
          int ec = (e < 40) ? e : 39;        // clamp addr; rows >=40 discarded
          const float* pa = xp + ec * 128 + ks * 32 + kg * 8;
          float4 a0 = *(const float4*)pa;
          float4 a1 = *(const float4*)(pa + 4);
          bf16x8 af;
          af[0] = (short)f2bf(a0.x); af[1] = (short)f2bf(a0.y);
          af[2] = (short)f2bf(a0.z); af[3] = (short)f2bf(a0.w);
          af[4] = (short)f2bf(a1.x); af[5] = (short)f2bf(a1.y);
          af[6] = (short)f2bf(a1.z); af[7] = (short)f2bf(a1.w);
          acc = __builtin_amdgcn_mfma_f32_16x16x32_bf16(af, bfrag, acc, 0, 0, 0);
        }
        // D layout: col = lane&15 (l), row = kg*4 + rg (e within 16-tile)
#pragma unroll
        for (int rg = 0; rg < 4; ++rg) {
          int e = et * 16 + kg * 4 + rg;
          if (e < 40) xds[e * 33 + lt2 * 16 + n16] = acc[rg];
        }
      }
    }
  }
  __syncthreads();

  const float* dtw = dir ? dtwb : dtwf;
  const float* dtb = dir ? dtbb : dtbf;
  u16* dlg = (u16*)(s + (dir ? ODLB : ODLF));
  for (int i = tid; i < 128 * 32; i += 256) {
    int d = i >> 5, li = i & 31;
    float pre = dtb[d];
#pragma unroll
    for (int r = 0; r < 8; ++r)
      pre = fmaf(dtw[d * 8 + r], xds[r * 33 + li], pre);
    dlg[(size_t)d * NL + lout0 + li] = f2bf(softplusf_(pre));
  }
  u16* bctp = (u16*)(s + OO2);
  for (int i = tid; i < 32 * 32; i += 256) {
    int li = i >> 5, k = i & 31;
    bctp[((size_t)dir * 4096 + lout0 + li) * 32 + k] = f2bf(xds[(8 + k) * 33 + li]);
  }
}

// 5a. Phase A: 16 d-rows/block; B-half of chunk bct staged to fp32 LDS;
// ushort8 dl/uc loads = 8 steps per load pair.
__global__ __launch_bounds__(256) void kscanA(
    const float* __restrict__ Alf, const float* __restrict__ Alb,
    float* __restrict__ ws) {
  int bi = blockIdx.y;
  float* s = ws + (size_t)bi * PER_B;
  int xid = blockIdx.x;
  int chunk = xid >> 4, dir = (xid >> 3) & 1, d8 = xid & 7;
  int tid = threadIdx.x;
  int wv = tid >> 6, lane = tid & 63;
  int n = lane & 15, g = lane >> 4;
  int d = d8 * 16 + wv * 4 + g;
  int l0 = chunk * CL;
  __shared__ float bl[CL * 16];
  {
    const u16* bctp = (const u16*)(s + OO2) + ((size_t)dir * 4096 + l0) * 32;
    for (int i = tid; i < CL * 16; i += 256) {
      int l = i >> 4, k = i & 15;
      bl[i] = __uint_as_float(((u32)bctp[l * 32 + k]) << 16);
    }
  }
  __syncthreads();
  const u16* ucp = (const u16*)(s + (dir ? OUCB : OUCF)) + (size_t)d * NL + l0;
  const u16* dlp = (const u16*)(s + (dir ? ODLB : ODLF)) + (size_t)d * NL + l0;
  float A = -__expf((dir ? Alb : Alf)[d * 16 + n]);
  float P = 1.f, S = 0.f;
  for (int i0 = 0; i0 < CL; i0 += 8) {
    uint4 dq = *(const uint4*)(dlp + i0);
    uint4 uq = *(const uint4*)(ucp + i0);
    float dv[8] = {bflo(dq.x), bfhi(dq.x), bflo(dq.y), bfhi(dq.y),
                   bflo(dq.z), bfhi(dq.z), bflo(dq.w), bfhi(dq.w)};
    float uv[8] = {bflo(uq.x), bfhi(uq.x), bflo(uq.y), bfhi(uq.y),
                   bflo(uq.z), bfhi(uq.z), bflo(uq.w), bfhi(uq.w)};
#pragma unroll
    for (int j = 0; j < 8; ++j) {
      float dA = __expf(dv[j] * A);
      S = fmaf(dA, S, dv[j] * bl[(i0 + j) * 16 + n] * uv[j]);
      P *= dA;
    }
  }
  size_t cidx = ((size_t)(chunk * 2 + dir) * 128 + d) * 16 + n;
  s[OO + cidx] = P;
  s[OO + 262144u + cidx] = S;
}

// 5c. Phase C: self-seeded re-scan (folds prior chunks' P/S inline -> no
// kscanB kernel); bf16 inputs; DPP row-sum; ps[16][65] staging.
__global__ __launch_bounds__(256) void kscanC(
    const float* __restrict__ Alf, const float* __restrict__ Df,
    const float* __restrict__ Alb, const float* __restrict__ Db,
    float* __restrict__ ws) {
  int bi = blockIdx.y;
  float* s = ws + (size_t)bi * PER_B;
  int xid = blockIdx.x;
  int chunk = xid >> 4, dir = (xid >> 3) & 1, d8 = xid & 7;
  int tid = threadIdx.x;
  int wv = tid >> 6, lane = tid & 63;
  int n = lane & 15, g = lane >> 4;
  int d = d8 * 16 + wv * 4 + g;
  int l0 = chunk * CL;
  __shared__ float bl[CL * 32];
  __shared__ float ps[16][65];
  {
    const u16* bctp = (const u16*)(s + OO2) + ((size_t)dir * 4096 + l0) * 32;
    for (int i = tid; i < CL * 32; i += 256)
      bl[i] = __uint_as_float(((u32)bctp[i]) << 16);
  }
  __syncthreads();
  const u16* ucp = (const u16*)(s + (dir ? OUCB : OUCF)) + (size_t)d * NL + l0;
  const u16* dlp = (const u16*)(s + (dir ? ODLB : ODLF)) + (size_t)d * NL + l0;
  float* ybase = s + (dir ? OYB : OYF);
  float A = -__expf((dir ? Alb : Alf)[d * 16 + n]);
  float Dv = (dir ? Db : Df)[d];
  // Self-seed: fold P/S of chunks < chunk for this (dir, d, n).
  float h = 0.f;
  {
    size_t stepi = (size_t)d * 16 + n;
#pragma unroll 4
    for (int c = 0; c < chunk; ++c) {
      size_t idx = ((size_t)(c * 2 + dir) * 128) * 16 + stepi;
      float pv = s[OO + idx], sv = s[OO + 262144u + idx];
      h = fmaf(pv, h, sv);
    }
  }
  int prow = wv * 4 + g;
  for (int i0 = 0; i0 < CL; i0 += 8) {
    uint4 dq = *(const uint4*)(dlp + i0);
    uint4 uq = *(const uint4*)(ucp + i0);
    float dv[8] = {bflo(dq.x), bfhi(dq.x), bflo(dq.y), bfhi(dq.y),
                   bflo(dq.z), bfhi(dq.z), bflo(dq.w), bfhi(dq.w)};
    float uv[8] = {bflo(uq.x), bfhi(uq.x), bflo(uq.y), bfhi(uq.y),
                   bflo(uq.z), bfhi(uq.z), bflo(uq.w), bfhi(uq.w)};
#pragma unroll
    for (int j = 0; j < 8; ++j) {
      int i = i0 + j;
      float dA = __expf(dv[j] * A);
      h = fmaf(dA, h, dv[j] * bl[i * 32 + n] * uv[j]);
      float p = rowsum16_(h * bl[i * 32 + 16 + n]);
      if (n == 0) ps[prow][i] = fmaf(uv[j], Dv, p);
    }
  }
  __syncthreads();
  for (int i = tid; i < 16 * CL; i += 256) {
    int row = i >> 6, col = i & 63;
    ybase[(size_t)(d8 * 16 + row) * NL + l0 + col] = ps[row][col];
  }
}

// 6. Fused gate + out-proj via MFMA. Block = 32-l tile.
// Gate: otb[l 32][d 128 pad 136] bf16 (transposed, 16B rows). Out-proj:
// D[c 64][l 32], K=128; wave ct handles both l2 tiles; float4 stores.
__global__ __launch_bounds__(256) void koutg(
    const float* __restrict__ wout, float* __restrict__ ws) {
  int bi = blockIdx.y;
  float* s = ws + (size_t)bi * PER_B;
  int lt = blockIdx.x;
  int l0 = lt * 32;
  int tid = threadIdx.x;
  __shared__ u16 otb[32][136];
  for (int i = tid; i < 128 * 32; i += 256) {
    int d = i >> 5, li = i & 31;
    int l = l0 + li;
    float z = s[OXZ + (size_t)(128 + d) * NL + l];
    float v = s[OYF + (size_t)d * NL + l] + s[OYB + (size_t)d * NL + (NL - 1 - l)];
    otb[li][d] = f2bf(v * siluf_(z));
  }
  __syncthreads();
  int wid = tid >> 6, lane = tid & 63;
  int n16 = lane & 15, kg = lane >> 4;
  f32x4 acc[2] = {};   // [l2 tile]
  const float* wr = wout + (size_t)(wid * 16 + n16) * 128 + kg * 8;
#pragma unroll
  for (int ks = 0; ks < 4; ++ks) {
    const float* pa = wr + ks * 32;
    float4 a0 = *(const float4*)pa;
    float4 a1 = *(const float4*)(pa + 4);
    bf16x8 af;
    af[0] = (short)f2bf(a0.x); af[1] = (short)f2bf(a0.y);
    af[2] = (short)f2bf(a0.z); af[3] = (short)f2bf(a0.w);
    af[4] = (short)f2bf(a1.x); af[5] = (short)f2bf(a1.y);
    af[6] = (short)f2bf(a1.z); af[7] = (short)f2bf(a1.w);
    bf16x8 b0 = *(const bf16x8*)&otb[n16][ks * 32 + kg * 8];
    bf16x8 b1 = *(const bf16x8*)&otb[16 + n16][ks * 32 + kg * 8];
    acc[0] = __builtin_amdgcn_mfma_f32_16x16x32_bf16(af, b0, acc[0], 0, 0, 0);
    acc[1] = __builtin_amdgcn_mfma_f32_16x16x32_bf16(af, b1, acc[1], 0, 0, 0);
  }
  // D: col = lane&15 (l), row = kg*4+rg (c in 16-tile); rg = consecutive c.
#pragma unroll
  for (int l2 = 0; l2 < 2; ++l2) {
    float4 st = make_float4(acc[l2][0], acc[l2][1], acc[l2][2], acc[l2][3]);
    *(float4*)&s[OO2 + (size_t)(l0 + l2 * 16 + n16) * 64 + wid * 16 + kg * 4] = st;
  }
}

// 6.5. Weight prep: Wbf8[xcd 8][27][co 64][ci 64] bf16 at ws + bcnt*PER_B.
// 8 replicas so each XCD's L2 caches its own copy (kconv3 picks bx&7).
__global__ __launch_bounds__(256) void kprepw(
    const float* __restrict__ pw, float* __restrict__ wdst) {
  int off = blockIdx.x;
  u16* wb = (u16*)wdst;
  int tid = threadIdx.x;
  for (int i = tid; i < 4096; i += 256) {
    int co = i >> 6, ci = i & 63;
    u16 v = f2bf(pw[(size_t)(co * 64 + ci) * 27 + off]);
#pragma unroll
    for (int xc = 0; xc < 8; ++xc)
      wb[(size_t)xc * WB1 + off * 4096 + i] = v;
  }
}

// 7. conv3d (bf16 implicit GEMM on MFMA) + FUSED 1x1x1 norm mix.
// Block tile [64 co][32 l] = one t-plane x 2 h-rows; grid = t(16) x hq(8),
// 512 blocks = 2/CU, 256 thr / 4 waves -> 8 waves/CU. Wave = 16co x 32l
// (2 MFMA per A-load, 2 indep chains). launch_bounds(256,2) caps 128 VGPR
// (R25's 32-VGPR collapse avoided) while guaranteeing 2-block residency.
// LDS: halo Xs[tt 3][hh 4][ww 18][ci 64 pad 72] bf16 (31.1 KB); after MFMA
// aliased as cx[ci 64][lp 32 pad 33] fp32, then 1x1x1 norm mix -> global.
__global__ __launch_bounds__(256, 2) void kconv3(
    const float* __restrict__ pb, const float* __restrict__ nw,
    const float* __restrict__ nb, const float* __restrict__ xin,
    float* __restrict__ out, const u16* __restrict__ wb,
    float* __restrict__ ws, int b0) {
  int bi = blockIdx.y, gb = b0 + bi;
  float* s = ws + (size_t)bi * PER_B;
  int bx = blockIdx.x;
  int t = bx >> 3, hq = bx & 7;
  int h0 = hq * 2;
  int tid = threadIdx.x;
  const float* xr = s + OO2;              // o2 in c-major reshape view

  __shared__ u16 Xs[3 * 4 * 18 * 72];     // 31104 B; later aliased as cx
  float* cx = (float*)Xs;                 // cx[64][33] = 8448 B
  // zero (covers t/h/w halo padding)
  {
    u32* xz32 = (u32*)Xs;
    for (int i = tid; i < 3 * 4 * 18 * 72 / 2; i += 256) xz32[i] = 0u;
  }
  __syncthreads();
  // stage valid rows, transposed to ci-contiguous bf16
  {
    int ci = tid >> 2, wq = tid & 3;
#pragma unroll
    for (int rowc = 0; rowc < 12; ++rowc) {
      int tt = rowc >> 2, hh = rowc & 3;
      int ts = t + tt - 1, hs = h0 + hh - 1;
      if (ts < 0 || ts > 15 || hs < 0 || hs > 15) continue;
      float4 v = *(const float4*)(xr + (size_t)ci * NL + ts * 256 + hs * 16 + wq * 4);
      int rb = (tt * 4 + hh) * 18 + 1 + wq * 4;
      Xs[(rb + 0) * 72 + ci] = f2bf(v.x);
      Xs[(rb + 1) * 72 + ci] = f2bf(v.y);
      Xs[(rb + 2) * 72 + ci] = f2bf(v.z);
      Xs[(rb + 3) * 72 + ci] = f2bf(v.w);
    }
  }
  __syncthreads();

  int wid = tid >> 6, lane = tid & 63;
  int cq = wid;                          // 16-co subtile per wave
  int n16 = lane & 15, kg = lane >> 4;   // k-group 0..3 (8 ci each)
  f32x4 acc[2] = {};                     // 2 l2 (h-row) chains

  // A: XCD-local replica; lane row co = cq*16 + n16, k = kg*8 + st*32 + j
  const u16* wbA = wb + (size_t)(bx & 7) * WB1 +
                   (size_t)(cq * 16 + n16) * 64 + kg * 8;
#pragma unroll
  for (int kt = 0; kt < 3; ++kt)
#pragma unroll
    for (int kh = 0; kh < 3; ++kh) {
#pragma unroll
      for (int kw = 0; kw < 3; ++kw) {
        int off = (kt * 3 + kh) * 3 + kw;
        const u16* pa = wbA + off * 4096;
#pragma unroll
        for (int st = 0; st < 2; ++st) {
          int kb = st * 32;
          bf16x8 a0 = *(const bf16x8*)(pa + kb);
#pragma unroll
          for (int l2 = 0; l2 < 2; ++l2) {
            int r = (kt * 4 + l2 + kh) * 18 + n16 + kw;
            bf16x8 b0 = *(const bf16x8*)(&Xs[r * 72 + kb + kg * 8]);
            acc[l2] = __builtin_amdgcn_mfma_f32_16x16x32_bf16(a0, b0, acc[l2], 0, 0, 0);
          }
        }
      }
    }
  __syncthreads();  // all Xs reads done; safe to overwrite with cx

  // cx[co][lp] = conv + bias + residual.
  // C/D layout: col = lane&15 (w), row = kg*4 + rg (co within 16-subtile)
#pragma unroll
  for (int l2 = 0; l2 < 2; ++l2) {
    int lp = l2 * 16 + n16;
    int lg = t * 256 + (h0 + l2) * 16 + n16;
#pragma unroll
    for (int rg = 0; rg < 4; ++rg) {
      int co = cq * 16 + kg * 4 + rg;
      cx[co * 33 + lp] = acc[l2][rg] + pb[co] +
                         xin[(size_t)(gb * 64 + co) * NL + lg];
    }
  }
  __syncthreads();

  // 1x1x1 norm mix: out[co2][lp] = nb + sum_ci nw[co2,ci] * cx[ci][lp]
  {
    int co2 = tid >> 2, pq = tid & 3;   // 8 l each
    float mac[8];
#pragma unroll
    for (int j = 0; j < 8; ++j) mac[j] = 0.f;
    for (int ci = 0; ci < 64; ci += 4) {
      float4 w4 = *(const float4*)&nw[co2 * 64 + ci];
      float wv[4] = {w4.x, w4.y, w4.z, w4.w};
#pragma unroll
      for (int cc = 0; cc < 4; ++cc) {
        const float* row = &cx[(ci + cc) * 33 + pq * 8];
        float4 a = *(const float4*)&row[0];
        float4 b = *(const float4*)&row[4];
        mac[0] = fmaf(wv[cc], a.x, mac[0]);  mac[1] = fmaf(wv[cc], a.y, mac[1]);
        mac[2] = fmaf(wv[cc], a.z, mac[2]);  mac[3] = fmaf(wv[cc], a.w, mac[3]);
        mac[4] = fmaf(wv[cc], b.x, mac[4]);  mac[5] = fmaf(wv[cc], b.y, mac[5]);
        mac[6] = fmaf(wv[cc], b.z, mac[6]);  mac[7] = fmaf(wv[cc], b.w, mac[7]);
      }
    }
    float bias = nb[co2];
    float4* dst = (float4*)(out + (size_t)(gb * 64 + co2) * NL +
                            t * 256 + h0 * 16 + pq * 8);
    dst[0] = make_float4(mac[0] + bias, mac[1] + bias, mac[2] + bias, mac[3] + bias);
    dst[1] = make_float4(mac[4] + bias, mac[5] + bias, mac[6] + bias, mac[7] + bias);
  }
}

// ---------------------------------------------------------------------------
extern "C" void kernel_launch(void* const* d_in, const int* in_sizes, int n_in,
                              void* d_out, int out_size, void* d_ws, size_t ws_size,
                              hipStream_t stream) {
  const float* x    = (const float*)d_in[0];
  const float* wip  = (const float*)d_in[1];
  const float* cwf  = (const float*)d_in[2];
  const float* cbf  = (const float*)d_in[3];
  const float* xpf  = (const float*)d_in[4];
  const float* dtwf = (const float*)d_in[5];
  const float* dtbf = (const float*)d_in[6];
  const float* Alf  = (const float*)d_in[7];
  const float* Df   = (const float*)d_in[8];
  const float* cwb  = (const float*)d_in[9];
  const float* cbb  = (const float*)d_in[10];
  const float* xpb  = (const float*)d_in[11];
  const float* dtwb = (const float*)d_in[12];
  const float* dtbb = (const float*)d_in[13];
  const float* Alb  = (const float*)d_in[14];
  const float* Db   = (const float*)d_in[15];
  const float* wout = (const float*)d_in[16];
  const float* pw   = (const float*)d_in[17];
  const float* pb   = (const float*)d_in[18];
  const float* nw   = (const float*)d_in[19];
  const float* nb   = (const float*)d_in[20];

  const size_t PER_B_BYTES = (size_t)PER_B * 4;  // 22,282,240 per batch slab
  const size_t WB_BYTES = 8u * WB1 * 2u;         // 1,769,472 (8 Wbf replicas)
  int bcnt;
  if (ws_size >= 4 * PER_B_BYTES + WB_BYTES) bcnt = 4;
  else if (ws_size >= PER_B_BYTES + WB_BYTES) bcnt = 1;
  else return;
  int passes = 4 / bcnt;

  float* ws = (float*)d_ws;
  float* wsW = ws + (size_t)bcnt * PER_B;
  kprepw<<<dim3(27), 256, 0, stream>>>(pw, wsW);
  for (int p = 0; p < passes; ++p) {
    int b0 = p * bcnt;
    kxz   <<<dim3(256, bcnt), 256, 0, stream>>>(x, wip, ws, b0);
    k2prep<<<dim3(256, bcnt), 256, 0, stream>>>(cwf, cbf, xpf, dtwf, dtbf,
                                                cwb, cbb, xpb, dtwb, dtbb, ws);
    kscanA<<<dim3(1024, bcnt), 256, 0, stream>>>(Alf, Alb, ws);
    kscanC<<<dim3(1024, bcnt), 256, 0, stream>>>(Alf, Df, Alb, Db, ws);
    koutg <<<dim3(128, bcnt), 256, 0, stream>>>(wout, ws);
    kconv3<<<dim3(128, bcnt), 256, 0, stream>>>(pb, nw, nb, x, (float*)d_out,
                                                (const u16*)wsW, ws, b0);
  }
}

// Round 8
// 257.838 us; speedup vs baseline: 1.0597x; 1.0000x over previous
//
#include <hip/hip_runtime.h>

// ---------------------------------------------------------------------------
// Bidirectional Mamba block, MI355X. Round 28:
//  - kscanA/kscanC instruction diet (kscanC was 48.7us, VALUBusy 78%, ~44
//    inst/step vs ~14 essential): (1) full 64-step unroll -> immediate LDS
//    offsets + pipelined global loads; (2) dl/uc stored fp32 (regions were 2x
//    oversized; kills 2 unpack ops/step + f2bf in k2prep; HBM at 9.7% so the
//    extra bytes are free; precision improves); (3) ps writes batched per 8
//    steps (one exec toggle instead of 8).
//  - R27 structure otherwise unchanged (kscanB eliminated, kconv3 2/CU etc).
// Shapes: B=4, C=64, D=128, L=4096 (l = h*256 + w*16 + t), N=16, R=8.
// ---------------------------------------------------------------------------

#define NL 4096

typedef unsigned short u16;
typedef unsigned int u32;
typedef __attribute__((ext_vector_type(8))) short bf16x8;
typedef __attribute__((ext_vector_type(4))) float f32x4;

__device__ __forceinline__ float siluf_(float x) {
  return x * __builtin_amdgcn_rcpf(1.f + __expf(-x));
}
__device__ __forceinline__ float softplusf_(float x) {
  return (x > 20.f) ? x : __logf(1.f + __expf(x));
}
__device__ __forceinline__ u16 f2bf(float f) {
  u32 u = __float_as_uint(f);
  u += 0x7fffu + ((u >> 16) & 1u);
  return (u16)(u >> 16);
}

// Sum over the 16-lane DPP row via rotations 1,2,4,8 (VALU pipe, no DS).
__device__ __forceinline__ float rowsum16_(float p) {
  int q;
  q = __builtin_amdgcn_mov_dpp(__float_as_int(p), 0x121, 0xf, 0xf, false);
  p += __int_as_float(q);
  q = __builtin_amdgcn_mov_dpp(__float_as_int(p), 0x122, 0xf, 0xf, false);
  p += __int_as_float(q);
  q = __builtin_amdgcn_mov_dpp(__float_as_int(p), 0x124, 0xf, 0xf, false);
  p += __int_as_float(q);
  q = __builtin_amdgcn_mov_dpp(__float_as_int(p), 0x128, 0xf, 0xf, false);
  p += __int_as_float(q);
  return p;
}

// Per-b slab offsets (fp32 elements)
#define OXZ  0u          // xz [256][4096] fp32
#define OUCF 1048576u    // ucf [128][4096] fp32
#define OUCB 1572864u    // ucb [128][4096] fp32 (flipped coords)
#define ODLF 2424832u    // dlf [128][4096] fp32
#define ODLB 2949120u    // dlb [128][4096] fp32 (flipped coords)
#define OYF  3473408u    // yf [128][4096] fp32
#define OYB  3997696u    // yb [128][4096] fp32 (flipped coords)
#define OO   4521984u    // scan scratch: P [262144] S [262144] fp32
#define OO2  5046272u    // bct bf16 until kscanC; then o2 [4096][64] fp32
#define PER_B 5570560u
// Wbf8 [8 xcd][27][64][64] bf16 lives at ws + bcnt*PER_B

#define NCH 64   // scan chunks
#define CL  64   // chunk length
#define WB1 110592u  // u16 elems per Wbf copy (27*64*64)

// 1. xz[e,l] = sum_c in_proj_w[e,c] * seq[c,l].
__global__ __launch_bounds__(256) void kxz(
    const float* __restrict__ x, const float* __restrict__ wip,
    float* __restrict__ ws, int b0) {
  int bi = blockIdx.y, gb = b0 + bi;
  float* s = ws + (size_t)bi * PER_B;
  int bid = blockIdx.x;
  int h = bid >> 4, w = bid & 15;
  int tid = threadIdx.x;
  __shared__ float xs[64][16];
  for (int i = tid; i < 1024; i += 256) {
    int c = i >> 4, t = i & 15;
    xs[c][t] = x[(size_t)(gb * 64 + c) * NL + t * 256 + h * 16 + w];
  }
  __syncthreads();
  int e = tid;
  float acc[16];
#pragma unroll
  for (int t = 0; t < 16; ++t) acc[t] = 0.f;
  for (int c = 0; c < 64; ++c) {
    float wv = wip[e * 64 + c];
#pragma unroll
    for (int t = 0; t < 16; ++t) acc[t] = fmaf(wv, xs[c][t], acc[t]);
  }
  float4* dst = (float4*)(s + OXZ + (size_t)e * NL + h * 256 + w * 16);
#pragma unroll
  for (int q = 0; q < 4; ++q)
    dst[q] = make_float4(acc[q * 4], acc[q * 4 + 1], acc[q * 4 + 2], acc[q * 4 + 3]);
}

// 2. Fused prep per (bi, dir, 32-l tile): dwconv+silu, x_dbl via MFMA, delta,
// bct. Grid x = 256 (lt 128 x dir 2). uc/dl now stored fp32.
__global__ __launch_bounds__(256) void k2prep(
    const float* __restrict__ cwf, const float* __restrict__ cbf,
    const float* __restrict__ xpf, const float* __restrict__ dtwf,
    const float* __restrict__ dtbf,
    const float* __restrict__ cwb, const float* __restrict__ cbb,
    const float* __restrict__ xpb, const float* __restrict__ dtwb,
    const float* __restrict__ dtbb,
    float* __restrict__ ws) {
  int bi = blockIdx.y;
  float* s = ws + (size_t)bi * PER_B;
  int bx = blockIdx.x;
  int lt = bx >> 1, dir = bx & 1;
  int l0 = lt * 32;
  int lout0 = dir ? (127 - lt) * 32 : l0;   // output base (flipped for bwd)
  int tid = threadIdx.x;

  __shared__ float pool[128 * 40];   // X[128][40] during dwconv; xds after
  __shared__ u16 uct[32][136];       // uc transposed bf16 (d-contig, 16B rows)
  float (*X)[40] = (float(*)[40])pool;

  for (int i = tid; i < 128 * 38; i += 256) {
    int d = i / 38, j = i - d * 38;
    int l = l0 - 3 + j;
    X[d][j] = (l >= 0 && l < NL) ? s[OXZ + (size_t)d * NL + l] : 0.f;
  }
  __syncthreads();

  const float* cw = dir ? cwb : cwf;
  const float* cb = dir ? cbb : cbf;
  float* ucg = s + (dir ? OUCB : OUCF);
  for (int i = tid; i < 128 * 32; i += 256) {
    int d = i >> 5, li = i & 31;
    float a = cb[d];
    if (dir == 0) {
#pragma unroll
      for (int k = 0; k < 4; ++k) a = fmaf(cw[d * 4 + k], X[d][li + k], a);
    } else {
#pragma unroll
      for (int k = 0; k < 4; ++k) a = fmaf(cw[d * 4 + k], X[d][37 - li - k], a);
    }
    a = siluf_(a);
    uct[li][d] = f2bf(a);
    ucg[(size_t)d * NL + lout0 + li] = a;
  }
  __syncthreads();  // X dead; pool becomes xds [40][33]

  // x_dbl via MFMA 16x16x32: D[e 48][l 32], K=128. Units (et,lt2) = 6 over
  // 4 waves (waves 0,1 take two units).
  float* xds = pool;
  {
    int wid = tid >> 6, lane = tid & 63;
    int n16 = lane & 15, kg = lane >> 4;
    const float* xp = dir ? xpb : xpf;
#pragma unroll
    for (int rep = 0; rep < 2; ++rep) {
      int id = wid + rep * 4;
      if (id < 6) {
        int et = id >> 1, lt2 = id & 1;
        f32x4 acc = {};
#pragma unroll
        for (int ks = 0; ks < 4; ++ks) {
          bf16x8 bfrag = *(const bf16x8*)&uct[lt2 * 16 + n16][ks * 32 + kg * 8];
          int e = et * 16 + n16;
          int ec = (e < 40) ? e : 39;        // clamp addr; rows >=40 discarded
          const float* pa = xp + ec * 128 + ks * 32 + kg * 8;
          float4 a0 = *(const float4*)pa;
          float4 a1 = *(const float4*)(pa + 4);
          bf16x8 af;
          af[0] = (short)f2bf(a0.x); af[1] = (short)f2bf(a0.y);
          af[2] = (short)f2bf(a0.z); af[3] = (short)f2bf(a0.w);
          af[4] = (short)f2bf(a1.x); af[5] = (short)f2bf(a1.y);
          af[6] = (short)f2bf(a1.z); af[7] = (short)f2bf(a1.w);
          acc = __builtin_amdgcn_mfma_f32_16x16x32_bf16(af, bfrag, acc, 0, 0, 0);
        }
        // D layout: col = lane&15 (l), row = kg*4 + rg (e within 16-tile)
#pragma unroll
        for (int rg = 0; rg < 4; ++rg) {
          int e = et * 16 + kg * 4 + rg;
          if (e < 40) xds[e * 33 + lt2 * 16 + n16] = acc[rg];
        }
      }
    }
  }
  __syncthreads();

  const float* dtw = dir ? dtwb : dtwf;
  const float* dtb = dir ? dtbb : dtbf;
  float* dlg = s + (dir ? ODLB : ODLF);
  for (int i = tid; i < 128 * 32; i += 256) {
    int d = i >> 5, li = i & 31;
    float pre = dtb[d];
#pragma unroll
    for (int r = 0; r < 8; ++r)
      pre = fmaf(dtw[d * 8 + r], xds[r * 33 + li], pre);
    dlg[(size_t)d * NL + lout0 + li] = softplusf_(pre);
  }
  u16* bctp = (u16*)(s + OO2);
  for (int i = tid; i < 32 * 32; i += 256) {
    int li = i >> 5, k = i & 31;
    bctp[((size_t)dir * 4096 + lout0 + li) * 32 + k] = f2bf(xds[(8 + k) * 33 + li]);
  }
}

// 5a. Phase A: 16 d-rows/block; B-half of chunk bct staged to fp32 LDS;
// fp32 dl/uc float4 loads; fully unrolled 64 steps (immediate offsets).
__global__ __launch_bounds__(256) void kscanA(
    const float* __restrict__ Alf, const float* __restrict__ Alb,
    float* __restrict__ ws) {
  int bi = blockIdx.y;
  float* s = ws + (size_t)bi * PER_B;
  int xid = blockIdx.x;
  int chunk = xid >> 4, dir = (xid >> 3) & 1, d8 = xid & 7;
  int tid = threadIdx.x;
  int wv = tid >> 6, lane = tid & 63;
  int n = lane & 15, g = lane >> 4;
  int d = d8 * 16 + wv * 4 + g;
  int l0 = chunk * CL;
  __shared__ float bl[CL * 16];
  {
    const u16* bctp = (const u16*)(s + OO2) + ((size_t)dir * 4096 + l0) * 32;
    for (int i = tid; i < CL * 16; i += 256) {
      int l = i >> 4, k = i & 15;
      bl[i] = __uint_as_float(((u32)bctp[l * 32 + k]) << 16);
    }
  }
  __syncthreads();
  const float* ucp = s + (dir ? OUCB : OUCF) + (size_t)d * NL + l0;
  const float* dlp = s + (dir ? ODLB : ODLF) + (size_t)d * NL + l0;
  const float* blB = bl + n;
  float A = -__expf((dir ? Alb : Alf)[d * 16 + n]);
  float P = 1.f, S = 0.f;
#pragma unroll
  for (int i0 = 0; i0 < CL; i0 += 8) {
    float4 dq0 = *(const float4*)(dlp + i0);
    float4 dq1 = *(const float4*)(dlp + i0 + 4);
    float4 uq0 = *(const float4*)(ucp + i0);
    float4 uq1 = *(const float4*)(ucp + i0 + 4);
    float dv[8] = {dq0.x, dq0.y, dq0.z, dq0.w, dq1.x, dq1.y, dq1.z, dq1.w};
    float uv[8] = {uq0.x, uq0.y, uq0.z, uq0.w, uq1.x, uq1.y, uq1.z, uq1.w};
#pragma unroll
    for (int j = 0; j < 8; ++j) {
      float dA = __expf(dv[j] * A);
      S = fmaf(dA, S, dv[j] * blB[(i0 + j) * 16] * uv[j]);
      P *= dA;
    }
  }
  size_t cidx = ((size_t)(chunk * 2 + dir) * 128 + d) * 16 + n;
  s[OO + cidx] = P;
  s[OO + 262144u + cidx] = S;
}

// 5c. Phase C: self-seeded re-scan; fp32 dl/uc; fully unrolled; DPP row-sum;
// ps writes batched per 8 steps.
__global__ __launch_bounds__(256) void kscanC(
    const float* __restrict__ Alf, const float* __restrict__ Df,
    const float* __restrict__ Alb, const float* __restrict__ Db,
    float* __restrict__ ws) {
  int bi = blockIdx.y;
  float* s = ws + (size_t)bi * PER_B;
  int xid = blockIdx.x;
  int chunk = xid >> 4, dir = (xid >> 3) & 1, d8 = xid & 7;
  int tid = threadIdx.x;
  int wv = tid >> 6, lane = tid & 63;
  int n = lane & 15, g = lane >> 4;
  int d = d8 * 16 + wv * 4 + g;
  int l0 = chunk * CL;
  __shared__ float bl[CL * 32];
  __shared__ float ps[16][65];
  {
    const u16* bctp = (const u16*)(s + OO2) + ((size_t)dir * 4096 + l0) * 32;
    for (int i = tid; i < CL * 32; i += 256)
      bl[i] = __uint_as_float(((u32)bctp[i]) << 16);
  }
  __syncthreads();
  const float* ucp = s + (dir ? OUCB : OUCF) + (size_t)d * NL + l0;
  const float* dlp = s + (dir ? ODLB : ODLF) + (size_t)d * NL + l0;
  const float* blB = bl + n;
  float* ybase = s + (dir ? OYB : OYF);
  float A = -__expf((dir ? Alb : Alf)[d * 16 + n]);
  float Dv = (dir ? Db : Df)[d];
  // Self-seed: fold P/S of chunks < chunk for this (dir, d, n).
  float h = 0.f;
  {
    size_t stepi = (size_t)d * 16 + n;
#pragma unroll 4
    for (int c = 0; c < chunk; ++c) {
      size_t idx = ((size_t)(c * 2 + dir) * 128) * 16 + stepi;
      float pv = s[OO + idx], sv = s[OO + 262144u + idx];
      h = fmaf(pv, h, sv);
    }
  }
  int prow = wv * 4 + g;
#pragma unroll
  for (int i0 = 0; i0 < CL; i0 += 8) {
    float4 dq0 = *(const float4*)(dlp + i0);
    float4 dq1 = *(const float4*)(dlp + i0 + 4);
    float4 uq0 = *(const float4*)(ucp + i0);
    float4 uq1 = *(const float4*)(ucp + i0 + 4);
    float dv[8] = {dq0.x, dq0.y, dq0.z, dq0.w, dq1.x, dq1.y, dq1.z, dq1.w};
    float uv[8] = {uq0.x, uq0.y, uq0.z, uq0.w, uq1.x, uq1.y, uq1.z, uq1.w};
    float yv[8];
#pragma unroll
    for (int j = 0; j < 8; ++j) {
      float dA = __expf(dv[j] * A);
      h = fmaf(dA, h, dv[j] * blB[(i0 + j) * 32] * uv[j]);
      float p = rowsum16_(h * blB[(i0 + j) * 32 + 16]);
      yv[j] = fmaf(uv[j], Dv, p);
    }
    if (n == 0) {
#pragma unroll
      for (int j = 0; j < 8; ++j) ps[prow][i0 + j] = yv[j];
    }
  }
  __syncthreads();
  for (int i = tid; i < 16 * CL; i += 256) {
    int row = i >> 6, col = i & 63;
    ybase[(size_t)(d8 * 16 + row) * NL + l0 + col] = ps[row][col];
  }
}

// 6. Fused gate + out-proj via MFMA. Block = 32-l tile.
__global__ __launch_bounds__(256) void koutg(
    const float* __restrict__ wout, float* __restrict__ ws) {
  int bi = blockIdx.y;
  float* s = ws + (size_t)bi * PER_B;
  int lt = blockIdx.x;
  int l0 = lt * 32;
  int tid = threadIdx.x;
  __shared__ u16 otb[32][136];
  for (int i = tid; i < 128 * 32; i += 256) {
    int d = i >> 5, li = i & 31;
    int l = l0 + li;
    float z = s[OXZ + (size_t)(128 + d) * NL + l];
    float v = s[OYF + (size_t)d * NL + l] + s[OYB + (size_t)d * NL + (NL - 1 - l)];
    otb[li][d] = f2bf(v * siluf_(z));
  }
  __syncthreads();
  int wid = tid >> 6, lane = tid & 63;
  int n16 = lane & 15, kg = lane >> 4;
  f32x4 acc[2] = {};   // [l2 tile]
  const float* wr = wout + (size_t)(wid * 16 + n16) * 128 + kg * 8;
#pragma unroll
  for (int ks = 0; ks < 4; ++ks) {
    const float* pa = wr + ks * 32;
    float4 a0 = *(const float4*)pa;
    float4 a1 = *(const float4*)(pa + 4);
    bf16x8 af;
    af[0] = (short)f2bf(a0.x); af[1] = (short)f2bf(a0.y);
    af[2] = (short)f2bf(a0.z); af[3] = (short)f2bf(a0.w);
    af[4] = (short)f2bf(a1.x); af[5] = (short)f2bf(a1.y);
    af[6] = (short)f2bf(a1.z); af[7] = (short)f2bf(a1.w);
    bf16x8 b0 = *(const bf16x8*)&otb[n16][ks * 32 + kg * 8];
    bf16x8 b1 = *(const bf16x8*)&otb[16 + n16][ks * 32 + kg * 8];
    acc[0] = __builtin_amdgcn_mfma_f32_16x16x32_bf16(af, b0, acc[0], 0, 0, 0);
    acc[1] = __builtin_amdgcn_mfma_f32_16x16x32_bf16(af, b1, acc[1], 0, 0, 0);
  }
  // D: col = lane&15 (l), row = kg*4+rg (c in 16-tile); rg = consecutive c.
#pragma unroll
  for (int l2 = 0; l2 < 2; ++l2) {
    float4 st = make_float4(acc[l2][0], acc[l2][1], acc[l2][2], acc[l2][3]);
    *(float4*)&s[OO2 + (size_t)(l0 + l2 * 16 + n16) * 64 + wid * 16 + kg * 4] = st;
  }
}

// 6.5. Weight prep: Wbf8[xcd 8][27][co 64][ci 64] bf16 at ws + bcnt*PER_B.
__global__ __launch_bounds__(256) void kprepw(
    const float* __restrict__ pw, float* __restrict__ wdst) {
  int off = blockIdx.x;
  u16* wb = (u16*)wdst;
  int tid = threadIdx.x;
  for (int i = tid; i < 4096; i += 256) {
    int co = i >> 6, ci = i & 63;
    u16 v = f2bf(pw[(size_t)(co * 64 + ci) * 27 + off]);
#pragma unroll
    for (int xc = 0; xc < 8; ++xc)
      wb[(size_t)xc * WB1 + off * 4096 + i] = v;
  }
}

// 7. conv3d (bf16 implicit GEMM on MFMA) + FUSED 1x1x1 norm mix. (R27 form.)
__global__ __launch_bounds__(256, 2) void kconv3(
    const float* __restrict__ pb, const float* __restrict__ nw,
    const float* __restrict__ nb, const float* __restrict__ xin,
    float* __restrict__ out, const u16* __restrict__ wb,
    float* __restrict__ ws, int b0) {
  int bi = blockIdx.y, gb = b0 + bi;
  float* s = ws + (size_t)bi * PER_B;
  int bx = blockIdx.x;
  int t = bx >> 3, hq = bx & 7;
  int h0 = hq * 2;
  int tid = threadIdx.x;
  const float* xr = s + OO2;              // o2 in c-major reshape view

  __shared__ u16 Xs[3 * 4 * 18 * 72];     // 31104 B; later aliased as cx
  float* cx = (float*)Xs;                 // cx[64][33] = 8448 B
  {
    u32* xz32 = (u32*)Xs;
    for (int i = tid; i < 3 * 4 * 18 * 72 / 2; i += 256) xz32[i] = 0u;
  }
  __syncthreads();
  {
    int ci = tid >> 2, wq = tid & 3;
#pragma unroll
    for (int rowc = 0; rowc < 12; ++rowc) {
      int tt = rowc >> 2, hh = rowc & 3;
      int ts = t + tt - 1, hs = h0 + hh - 1;
      if (ts < 0 || ts > 15 || hs < 0 || hs > 15) continue;
      float4 v = *(const float4*)(xr + (size_t)ci * NL + ts * 256 + hs * 16 + wq * 4);
      int rb = (tt * 4 + hh) * 18 + 1 + wq * 4;
      Xs[(rb + 0) * 72 + ci] = f2bf(v.x);
      Xs[(rb + 1) * 72 + ci] = f2bf(v.y);
      Xs[(rb + 2) * 72 + ci] = f2bf(v.z);
      Xs[(rb + 3) * 72 + ci] = f2bf(v.w);
    }
  }
  __syncthreads();

  int wid = tid >> 6, lane = tid & 63;
  int cq = wid;
  int n16 = lane & 15, kg = lane >> 4;
  f32x4 acc[2] = {};

  const u16* wbA = wb + (size_t)(bx & 7) * WB1 +
                   (size_t)(cq * 16 + n16) * 64 + kg * 8;
#pragma unroll
  for (int kt = 0; kt < 3; ++kt)
#pragma unroll
    for (int kh = 0; kh < 3; ++kh) {
#pragma unroll
      for (int kw = 0; kw < 3; ++kw) {
        int off = (kt * 3 + kh) * 3 + kw;
        const u16* pa = wbA + off * 4096;
#pragma unroll
        for (int st = 0; st < 2; ++st) {
          int kb = st * 32;
          bf16x8 a0 = *(const bf16x8*)(pa + kb);
#pragma unroll
          for (int l2 = 0; l2 < 2; ++l2) {
            int r = (kt * 4 + l2 + kh) * 18 + n16 + kw;
            bf16x8 b0 = *(const bf16x8*)(&Xs[r * 72 + kb + kg * 8]);
            acc[l2] = __builtin_amdgcn_mfma_f32_16x16x32_bf16(a0, b0, acc[l2], 0, 0, 0);
          }
        }
      }
    }
  __syncthreads();

#pragma unroll
  for (int l2 = 0; l2 < 2; ++l2) {
    int lp = l2 * 16 + n16;
    int lg = t * 256 + (h0 + l2) * 16 + n16;
#pragma unroll
    for (int rg = 0; rg < 4; ++rg) {
      int co = cq * 16 + kg * 4 + rg;
      cx[co * 33 + lp] = acc[l2][rg] + pb[co] +
                         xin[(size_t)(gb * 64 + co) * NL + lg];
    }
  }
  __syncthreads();

  {
    int co2 = tid >> 2, pq = tid & 3;
    float mac[8];
#pragma unroll
    for (int j = 0; j < 8; ++j) mac[j] = 0.f;
    for (int ci = 0; ci < 64; ci += 4) {
      float4 w4 = *(const float4*)&nw[co2 * 64 + ci];
      float wv[4] = {w4.x, w4.y, w4.z, w4.w};
#pragma unroll
      for (int cc = 0; cc < 4; ++cc) {
        const float* row = &cx[(ci + cc) * 33 + pq * 8];
        float4 a = *(const float4*)&row[0];
        float4 b = *(const float4*)&row[4];
        mac[0] = fmaf(wv[cc], a.x, mac[0]);  mac[1] = fmaf(wv[cc], a.y, mac[1]);
        mac[2] = fmaf(wv[cc], a.z, mac[2]);  mac[3] = fmaf(wv[cc], a.w, mac[3]);
        mac[4] = fmaf(wv[cc], b.x, mac[4]);  mac[5] = fmaf(wv[cc], b.y, mac[5]);
        mac[6] = fmaf(wv[cc], b.z, mac[6]);  mac[7] = fmaf(wv[cc], b.w, mac[7]);
      }
    }
    float bias = nb[co2];
    float4* dst = (float4*)(out + (size_t)(gb * 64 + co2) * NL +
                            t * 256 + h0 * 16 + pq * 8);
    dst[0] = make_float4(mac[0] + bias, mac[1] + bias, mac[2] + bias, mac[3] + bias);
    dst[1] = make_float4(mac[4] + bias, mac[5] + bias, mac[6] + bias, mac[7] + bias);
  }
}

// ---------------------------------------------------------------------------
extern "C" void kernel_launch(void* const* d_in, const int* in_sizes, int n_in,
                              void* d_out, int out_size, void* d_ws, size_t ws_size,
                              hipStream_t stream) {
  const float* x    = (const float*)d_in[0];
  const float* wip  = (const float*)d_in[1];
  const float* cwf  = (const float*)d_in[2];
  const float* cbf  = (const float*)d_in[3];
  const float* xpf  = (const float*)d_in[4];
  const float* dtwf = (const float*)d_in[5];
  const float* dtbf = (const float*)d_in[6];
  const float* Alf  = (const float*)d_in[7];
  const float* Df   = (const float*)d_in[8];
  const float* cwb  = (const float*)d_in[9];
  const float* cbb  = (const float*)d_in[10];
  const float* xpb  = (const float*)d_in[11];
  const float* dtwb = (const float*)d_in[12];
  const float* dtbb = (const float*)d_in[13];
  const float* Alb  = (const float*)d_in[14];
  const float* Db   = (const float*)d_in[15];
  const float* wout = (const float*)d_in[16];
  const float* pw   = (const float*)d_in[17];
  const float* pb   = (const float*)d_in[18];
  const float* nw   = (const float*)d_in[19];
  const float* nb   = (const float*)d_in[20];

  const size_t PER_B_BYTES = (size_t)PER_B * 4;  // 22,282,240 per batch slab
  const size_t WB_BYTES = 8u * WB1 * 2u;         // 1,769,472 (8 Wbf replicas)
  int bcnt;
  if (ws_size >= 4 * PER_B_BYTES + WB_BYTES) bcnt = 4;
  else if (ws_size >= PER_B_BYTES + WB_BYTES) bcnt = 1;
  else return;
  int passes = 4 / bcnt;

  float* ws = (float*)d_ws;
  float* wsW = ws + (size_t)bcnt * PER_B;
  kprepw<<<dim3(27), 256, 0, stream>>>(pw, wsW);
  for (int p = 0; p < passes; ++p) {
    int b0 = p * bcnt;
    kxz   <<<dim3(256, bcnt), 256, 0, stream>>>(x, wip, ws, b0);
    k2prep<<<dim3(256, bcnt), 256, 0, stream>>>(cwf, cbf, xpf, dtwf, dtbf,
                                                cwb, cbb, xpb, dtwb, dtbb, ws);
    kscanA<<<dim3(1024, bcnt), 256, 0, stream>>>(Alf, Alb, ws);
    kscanC<<<dim3(1024, bcnt), 256, 0, stream>>>(Alf, Df, Alb, Db, ws);
    koutg <<<dim3(128, bcnt), 256, 0, stream>>>(wout, ws);
    kconv3<<<dim3(128, bcnt), 256, 0, stream>>>(pb, nw, nb, x, (float*)d_out,
                                                (const u16*)wsW, ws, b0);
  }
}